// Round 2
// baseline (1697.622 us; speedup 1.0000x reference)
//
#include <hip/hip_runtime.h>
#include <hip/hip_bf16.h>
#include <math.h>

// All inputs/outputs are float32 per the reference (setup_inputs uses jnp.float32).
// Problem constants: B=4, S=1024, D=1024, H=16, KVH=4, HD=64, HIDDEN=1024, BLK=8
#define SEQ 1024
#define DIM 1024

constexpr int BM = 64, BN = 64, BKT = 16;

// EPI: 0 plain->f32  1 rope->f32  2 +bias->f32
//      3 x + gate*acc -> f32 (h)     4 h + gate*acc -> f32 (final out)
template<bool SILU, int EPI>
__global__ __launch_bounds__(256) void gemm64(
    const float* __restrict__ A, const float* __restrict__ W,
    int M, int N, int K,
    float* __restrict__ outF,
    const float* __restrict__ bias,
    const float* __restrict__ xres,
    const float* __restrict__ hres,
    const float* __restrict__ mod,
    const float* __restrict__ fcos, const float* __restrict__ fsin)
{
  __shared__ float As[BKT][BM + 1];
  __shared__ float Bs[BKT][BN + 1];
  const int tid = threadIdx.x;
  const int tx = tid & 15, ty = tid >> 4;
  const int rowBlk = blockIdx.y * BM;
  const int colBlk = blockIdx.x * BN;
  const int lj = tid & 15;   // k within tile
  const int li = tid >> 4;   // row base (16 rows/pass)
  float acc[4][4] = {};
  for (int k0 = 0; k0 < K; k0 += BKT) {
#pragma unroll
    for (int p = 0; p < 4; ++p) {
      int rr = li + p * 16;
      float av = A[(size_t)(rowBlk + rr) * K + k0 + lj];
      if (SILU) av = av / (1.0f + expf(-av));
      As[lj][rr] = av;
      Bs[lj][rr] = W[(size_t)(colBlk + rr) * K + k0 + lj];
    }
    __syncthreads();
#pragma unroll
    for (int kk = 0; kk < BKT; ++kk) {
      float a[4], b[4];
#pragma unroll
      for (int m = 0; m < 4; ++m) a[m] = As[kk][ty * 4 + m];
#pragma unroll
      for (int n = 0; n < 4; ++n) b[n] = Bs[kk][tx * 4 + n];
#pragma unroll
      for (int m = 0; m < 4; ++m)
#pragma unroll
        for (int n = 0; n < 4; ++n) acc[m][n] = fmaf(a[m], b[n], acc[m][n]);
    }
    __syncthreads();
  }

  const int row = rowBlk + ty * 4;
  const int col = colBlk + tx * 4;

  if constexpr (EPI == 0) {
#pragma unroll
    for (int m = 0; m < 4; ++m) {
      float* o = outF + (size_t)(row + m) * N + col;
#pragma unroll
      for (int n = 0; n < 4; ++n) o[n] = acc[m][n];
    }
  } else if constexpr (EPI == 1) {
#pragma unroll
    for (int m = 0; m < 4; ++m) {
      int r = row + m;
      int s = r & (SEQ - 1);
#pragma unroll
      for (int p = 0; p < 2; ++p) {
        int c = col + 2 * p;
        int t = (c & 63) >> 1;
        float cv = fcos[(size_t)s * 32 + t];
        float sv = fsin[(size_t)s * 32 + t];
        float x1 = acc[m][2 * p], x2 = acc[m][2 * p + 1];
        outF[(size_t)r * N + c]     = x1 * cv - x2 * sv;
        outF[(size_t)r * N + c + 1] = x1 * sv + x2 * cv;
      }
    }
  } else if constexpr (EPI == 2) {
#pragma unroll
    for (int m = 0; m < 4; ++m) {
      float* o = outF + (size_t)(row + m) * N + col;
#pragma unroll
      for (int n = 0; n < 4; ++n) o[n] = acc[m][n] + bias[col + n];
    }
  } else if constexpr (EPI == 3) {
#pragma unroll
    for (int m = 0; m < 4; ++m) {
      int r = row + m;
      int vr = (r >> 10) * 128 + ((r & (SEQ - 1)) >> 3);
      const float* gmod = mod + (size_t)vr * 3072 + 2048;
#pragma unroll
      for (int n = 0; n < 4; ++n) {
        int c = col + n;
        outF[(size_t)r * DIM + c] =
            xres[(size_t)r * DIM + c] + gmod[c] * acc[m][n];
      }
    }
  } else if constexpr (EPI == 4) {
#pragma unroll
    for (int m = 0; m < 4; ++m) {
      int r = row + m;
      int vr = (r >> 10) * 128 + ((r & (SEQ - 1)) >> 3);
      const float* gmod = mod + (size_t)vr * 3072 + 2048;
#pragma unroll
      for (int n = 0; n < 4; ++n) {
        int c = col + n;
        outF[(size_t)r * DIM + c] =
            hres[(size_t)r * DIM + c] + gmod[c] * acc[m][n];
      }
    }
  }
}

// hn = rmsnorm(x)*w*(1+scale) + shift ; scale/shift from mod rows (per 8-token block)
__global__ __launch_bounds__(256) void rms_mod(
    const float* __restrict__ X, const float* __restrict__ w,
    const float* __restrict__ mod, float* __restrict__ out)
{
  const int r = blockIdx.x;
  const int b = r >> 10, s = r & (SEQ - 1);
  const int vr = b * 128 + (s >> 3);
  const size_t base = (size_t)r * DIM;
  float v[4];
  float ss = 0.f;
#pragma unroll
  for (int p = 0; p < 4; ++p) {
    int c = threadIdx.x + p * 256;
    v[p] = X[base + c];
    ss += v[p] * v[p];
  }
#pragma unroll
  for (int off = 1; off < 64; off <<= 1) ss += __shfl_xor(ss, off);
  __shared__ float red[4];
  int lane = threadIdx.x & 63, wv = threadIdx.x >> 6;
  if (lane == 0) red[wv] = ss;
  __syncthreads();
  float total = red[0] + red[1] + red[2] + red[3];
  float rn = rsqrtf(total * (1.0f / 1024.0f) + 1e-6f);
  const float* mrow = mod + (size_t)vr * 3072;
#pragma unroll
  for (int p = 0; p < 4; ++p) {
    int c = threadIdx.x + p * 256;
    out[base + c] = v[p] * rn * w[c] * (1.0f + mrow[1024 + c]) + mrow[c];
  }
}

// Flash-style block-causal attention. One block per (b, h, q-tile of 64).
// Q (4096x1024) f32 [b*S+s, h*64+d]; K,V (4096x256) f32 [b*S+s, kvh*64+d].
__global__ __launch_bounds__(256) void attn_kernel(
    const float* __restrict__ Q, const float* __restrict__ Kg,
    const float* __restrict__ V, float* __restrict__ O)
{
  const int bid = blockIdx.x;
  const int qt = bid & 15;
  const int h = (bid >> 4) & 15;
  const int b = bid >> 8;
  const int kvh = h >> 2;
  __shared__ float Qs[64][65];
  __shared__ float Ks[64][65];  // reused for P after scores
  __shared__ float Vs[64][65];
  const int tid = threadIdx.x;
  const int tx = tid & 15, ty = tid >> 4;

  for (int idx = tid; idx < 64 * 64; idx += 256) {
    int i = idx >> 6, d = idx & 63;
    Qs[i][d] = Q[(size_t)(b * SEQ + qt * 64 + i) * DIM + h * 64 + d];
  }
  float acc[4][4] = {};
  float m_r[4], l_r[4];
#pragma unroll
  for (int m = 0; m < 4; ++m) { m_r[m] = -1e30f; l_r[m] = 0.f; }

  for (int kt = 0; kt <= qt; ++kt) {
    __syncthreads();  // protect Ks/Vs from prior-iter readers + Q load on iter 0
    for (int idx = tid; idx < 64 * 64; idx += 256) {
      int j = idx >> 6, d = idx & 63;
      size_t roff = (size_t)(b * SEQ + kt * 64 + j) * 256 + kvh * 64 + d;
      Ks[j][d] = Kg[roff];
      Vs[j][d] = V[roff];
    }
    __syncthreads();
    // scores: queries ty*4+m, keys tx*4+n
    float s[4][4] = {};
    for (int d = 0; d < 64; ++d) {
      float a[4], kk[4];
#pragma unroll
      for (int m = 0; m < 4; ++m) a[m] = Qs[ty * 4 + m][d];
#pragma unroll
      for (int n = 0; n < 4; ++n) kk[n] = Ks[tx * 4 + n][d];
#pragma unroll
      for (int m = 0; m < 4; ++m)
#pragma unroll
        for (int n = 0; n < 4; ++n) s[m][n] = fmaf(a[m], kk[n], s[m][n]);
    }
    // scale + block-causal mask (diagonal tile only)
#pragma unroll
    for (int m = 0; m < 4; ++m)
#pragma unroll
      for (int n = 0; n < 4; ++n) {
        float val = s[m][n] * 0.125f;
        if (kt == qt && ((tx * 4 + n) >> 3) > ((ty * 4 + m) >> 3)) val = -1e9f;
        s[m][n] = val;
      }
    // online softmax; rows reduced across the 16 lanes sharing ty
    float p[4][4], alpha[4];
#pragma unroll
    for (int m = 0; m < 4; ++m) {
      float rmax = fmaxf(fmaxf(s[m][0], s[m][1]), fmaxf(s[m][2], s[m][3]));
#pragma unroll
      for (int off = 1; off < 16; off <<= 1) rmax = fmaxf(rmax, __shfl_xor(rmax, off));
      float mnew = fmaxf(m_r[m], rmax);
      alpha[m] = expf(m_r[m] - mnew);
      float rsum = 0.f;
#pragma unroll
      for (int n = 0; n < 4; ++n) { p[m][n] = expf(s[m][n] - mnew); rsum += p[m][n]; }
#pragma unroll
      for (int off = 1; off < 16; off <<= 1) rsum += __shfl_xor(rsum, off);
      l_r[m] = l_r[m] * alpha[m] + rsum;
      m_r[m] = mnew;
    }
    __syncthreads();  // everyone done reading Ks
#pragma unroll
    for (int m = 0; m < 4; ++m)
#pragma unroll
      for (int n = 0; n < 4; ++n) Ks[ty * 4 + m][tx * 4 + n] = p[m][n];
#pragma unroll
    for (int m = 0; m < 4; ++m)
#pragma unroll
      for (int n = 0; n < 4; ++n) acc[m][n] *= alpha[m];
    __syncthreads();  // P visible
    for (int j = 0; j < 64; ++j) {
      float pm[4], vn[4];
#pragma unroll
      for (int m = 0; m < 4; ++m) pm[m] = Ks[ty * 4 + m][j];
#pragma unroll
      for (int n = 0; n < 4; ++n) vn[n] = Vs[j][tx * 4 + n];
#pragma unroll
      for (int m = 0; m < 4; ++m)
#pragma unroll
        for (int n = 0; n < 4; ++n) acc[m][n] = fmaf(pm[m], vn[n], acc[m][n]);
    }
  }
#pragma unroll
  for (int m = 0; m < 4; ++m) {
    float inv = 1.0f / l_r[m];
    float* o = O + (size_t)(b * SEQ + qt * 64 + ty * 4 + m) * DIM + h * 64 + tx * 4;
#pragma unroll
    for (int n = 0; n < 4; ++n) o[n] = acc[m][n] * inv;
  }
}

// g = silu(hn@w1^T) * (hn@w3^T)
__global__ __launch_bounds__(256) void ffn13_gemm(
    const float* __restrict__ A, const float* __restrict__ W1,
    const float* __restrict__ W3, float* __restrict__ G, int M, int N, int K)
{
  __shared__ float As[BKT][BM + 1];
  __shared__ float B1[BKT][BN + 1];
  __shared__ float B3[BKT][BN + 1];
  const int tid = threadIdx.x;
  const int tx = tid & 15, ty = tid >> 4;
  const int rowBlk = blockIdx.y * BM;
  const int colBlk = blockIdx.x * BN;
  const int lj = tid & 15;
  const int li = tid >> 4;
  float acc1[4][4] = {}, acc3[4][4] = {};
  for (int k0 = 0; k0 < K; k0 += BKT) {
#pragma unroll
    for (int p = 0; p < 4; ++p) {
      int rr = li + p * 16;
      As[lj][rr] = A[(size_t)(rowBlk + rr) * K + k0 + lj];
      B1[lj][rr] = W1[(size_t)(colBlk + rr) * K + k0 + lj];
      B3[lj][rr] = W3[(size_t)(colBlk + rr) * K + k0 + lj];
    }
    __syncthreads();
#pragma unroll
    for (int kk = 0; kk < BKT; ++kk) {
      float a[4], b1[4], b3[4];
#pragma unroll
      for (int m = 0; m < 4; ++m) a[m] = As[kk][ty * 4 + m];
#pragma unroll
      for (int n = 0; n < 4; ++n) { b1[n] = B1[kk][tx * 4 + n]; b3[n] = B3[kk][tx * 4 + n]; }
#pragma unroll
      for (int m = 0; m < 4; ++m)
#pragma unroll
        for (int n = 0; n < 4; ++n) {
          acc1[m][n] = fmaf(a[m], b1[n], acc1[m][n]);
          acc3[m][n] = fmaf(a[m], b3[n], acc3[m][n]);
        }
    }
    __syncthreads();
  }
  const int row = rowBlk + ty * 4;
  const int col = colBlk + tx * 4;
#pragma unroll
  for (int m = 0; m < 4; ++m) {
    float* o = G + (size_t)(row + m) * N + col;
#pragma unroll
    for (int n = 0; n < 4; ++n) {
      float u = acc1[m][n];
      float sil = u / (1.0f + expf(-u));
      o[n] = sil * acc3[m][n];
    }
  }
}

extern "C" void kernel_launch(void* const* d_in, const int* in_sizes, int n_in,
                              void* d_out, int out_size, void* d_ws, size_t ws_size,
                              hipStream_t stream)
{
  const float* x   = (const float*)d_in[0];
  const float* vec = (const float*)d_in[1];
  const float* wq  = (const float*)d_in[2];
  const float* wk  = (const float*)d_in[3];
  const float* wv  = (const float*)d_in[4];
  const float* wo  = (const float*)d_in[5];
  const float* w1  = (const float*)d_in[6];
  const float* w2  = (const float*)d_in[7];
  const float* w3  = (const float*)d_in[8];
  const float* maw = (const float*)d_in[9];
  const float* mab = (const float*)d_in[10];
  const float* mfw = (const float*)d_in[11];
  const float* mfb = (const float*)d_in[12];
  const float* n1w = (const float*)d_in[13];
  const float* n2w = (const float*)d_in[14];
  const float* fc  = (const float*)d_in[15];
  const float* fs  = (const float*)d_in[16];

  float* ws = (float*)d_ws;
  // Buffer plan (floats). 4096 = B*S rows.
  float* XN   = ws;                         // 4096*1024 : xn -> attn_out -> g
  float* Qb   = XN + (size_t)4096 * 1024;   // 4096*1024 : q  -> hn
  float* Kb   = Qb + (size_t)4096 * 1024;   // 4096*256
  float* Vb   = Kb + (size_t)4096 * 256;    // 4096*256
  float* Hb   = Vb + (size_t)4096 * 256;    // 4096*1024 : h
  float* MODA = Hb + (size_t)4096 * 1024;   // 512*3072
  float* MODF = MODA + (size_t)512 * 3072;  // 512*3072
  // total 17.83M floats = 71.3 MB

  dim3 blk(256);

  // modulation GEMMs: silu(vec) @ modW^T + b
  gemm64<true, 2><<<dim3(48, 8), blk, 0, stream>>>(
      vec, maw, 512, 3072, 1024, MODA, mab, nullptr, nullptr, nullptr, nullptr, nullptr);
  gemm64<true, 2><<<dim3(48, 8), blk, 0, stream>>>(
      vec, mfw, 512, 3072, 1024, MODF, mfb, nullptr, nullptr, nullptr, nullptr, nullptr);

  // xn = rmsnorm(x)*(1+sc_a)+sh_a
  rms_mod<<<4096, blk, 0, stream>>>(x, n1w, MODA, XN);

  // q/k/v with fused RoPE (q,k)
  gemm64<false, 1><<<dim3(16, 64), blk, 0, stream>>>(
      XN, wq, 4096, 1024, 1024, Qb, nullptr, nullptr, nullptr, nullptr, fc, fs);
  gemm64<false, 1><<<dim3(4, 64), blk, 0, stream>>>(
      XN, wk, 4096, 256, 1024, Kb, nullptr, nullptr, nullptr, nullptr, fc, fs);
  gemm64<false, 0><<<dim3(4, 64), blk, 0, stream>>>(
      XN, wv, 4096, 256, 1024, Vb, nullptr, nullptr, nullptr, nullptr, nullptr, nullptr);

  // block-causal flash attention -> XN (attn_out)
  attn_kernel<<<1024, blk, 0, stream>>>(Qb, Kb, Vb, XN);

  // h = x + gate_a * (attn_out @ wo^T)
  gemm64<false, 3><<<dim3(16, 64), blk, 0, stream>>>(
      XN, wo, 4096, 1024, 1024, Hb, nullptr, x, nullptr, MODA, nullptr, nullptr);

  // hn = rmsnorm(h)*(1+sc_f)+sh_f  -> Qb
  rms_mod<<<4096, blk, 0, stream>>>(Hb, n2w, MODF, Qb);

  // g = silu(hn@w1^T) * (hn@w3^T)  -> XN
  ffn13_gemm<<<dim3(16, 64), blk, 0, stream>>>(Qb, w1, w3, XN, 4096, 1024, 1024);

  // out = h + gate_f * (g @ w2^T)  (f32)
  gemm64<false, 4><<<dim3(16, 64), blk, 0, stream>>>(
      XN, w2, 4096, 1024, 1024, (float*)d_out, nullptr, nullptr, Hb, MODF, nullptr, nullptr);
}

// Round 3
// 714.517 us; speedup vs baseline: 2.3759x; 2.3759x over previous
//
#include <hip/hip_runtime.h>
#include <math.h>

// B=4, S=1024, D=1024, H=16, KVH=4, HD=64, HIDDEN=1024, BLK=8
#define SEQ 1024
#define DIM 1024

using short8 = __attribute__((ext_vector_type(8))) short;
using f32x4  = __attribute__((ext_vector_type(4))) float;

__device__ __forceinline__ unsigned short f2bf(float f) {
  unsigned int u = __float_as_uint(f);
  u = (u + 0x7FFFu + ((u >> 16) & 1u)) >> 16;
  return (unsigned short)u;
}
__device__ __forceinline__ float bf2f(unsigned short h) {
  return __uint_as_float(((unsigned int)h) << 16);
}
__device__ __forceinline__ void load16_lds(const unsigned short* g, unsigned short* l) {
  __builtin_amdgcn_global_load_lds((const __attribute__((address_space(1))) void*)g,
                                   (__attribute__((address_space(3))) void*)l, 16, 0, 0);
}

// ---------------- weight cast (f32 -> bf16), 9 regions ----------------
struct CastArgs {
  const float* src[9];
  unsigned short* dst[9];
  int n[9];
};
__global__ __launch_bounds__(256) void cast_weights(CastArgs a) {
  int r = blockIdx.y;
  int i4 = (blockIdx.x * 256 + threadIdx.x) * 4;
  if (i4 >= a.n[r]) return;
  const float4 v = *(const float4*)(a.src[r] + i4);
  ushort4 o;
  o.x = f2bf(v.x); o.y = f2bf(v.y); o.z = f2bf(v.z); o.w = f2bf(v.w);
  *(ushort4*)(a.dst[r] + i4) = o;
}

// ---------------- silu(vec) -> bf16 ----------------
__global__ __launch_bounds__(256) void silu_cast(const float* __restrict__ v,
                                                 unsigned short* __restrict__ o, int n) {
  int i4 = (blockIdx.x * 256 + threadIdx.x) * 4;
  if (i4 >= n) return;
  float4 x = *(const float4*)(v + i4);
  ushort4 r;
  r.x = f2bf(x.x / (1.0f + expf(-x.x)));
  r.y = f2bf(x.y / (1.0f + expf(-x.y)));
  r.z = f2bf(x.z / (1.0f + expf(-x.z)));
  r.w = f2bf(x.w / (1.0f + expf(-x.w)));
  *(ushort4*)(o + i4) = r;
}

// ---------------- MFMA GEMM: C[M,N] = A[M,K] @ W[N,K]^T (A,W bf16) ----------------
// 128x128 block tile, 4 waves (2x2) each 64x64, BK=32, global_load_lds width 16.
// EPI: 0 QKV(+RoPE)->bf16[N=1536]  1 +bias->f32  2 x+gate*acc->f32 (h)
//      3 plain->bf16               4 h+gate*acc->f32 (final)
template<int EPI>
__global__ __launch_bounds__(256) void mfma_gemm(
    const unsigned short* __restrict__ A, const unsigned short* __restrict__ W,
    int M, int N, int K,
    float* __restrict__ outF, unsigned short* __restrict__ outBF,
    const float* __restrict__ aux1,   // bias / xres / hres
    const float* __restrict__ aux2,   // mod base (gate at +2048)
    const float* __restrict__ fc, const float* __restrict__ fs)
{
  __shared__ unsigned short sA[128 * 32];
  __shared__ unsigned short sB[128 * 32];
  const int tid = threadIdx.x;
  const int lane = tid & 63;
  const int wv = tid >> 6;          // 0..3
  const int wr = wv >> 1, wc = wv & 1;
  const int rowBlk = blockIdx.y * 128;
  const int colBlk = blockIdx.x * 128;
  const int l4 = lane >> 2;         // row within 16-row chunk
  const int lk = (lane & 3) * 8;    // k element offset (8 bf16 = 16B)
  const int q = lane >> 4;          // quad
  const int cl = lane & 15;

  f32x4 acc[4][4] = {};

  for (int k0 = 0; k0 < K; k0 += 32) {
#pragma unroll
    for (int c = 0; c < 2; ++c) {
      int ch = wv * 2 + c;          // chunk 0..7 (16 rows each)
      int row = ch * 16 + l4;
      load16_lds(A + (size_t)(rowBlk + row) * K + k0 + lk, &sA[ch * 512 + lane * 8]);
      load16_lds(W + (size_t)(colBlk + row) * K + k0 + lk, &sB[ch * 512 + lane * 8]);
    }
    __syncthreads();
    short8 af[4], bfr[4];
#pragma unroll
    for (int t = 0; t < 4; ++t) {
      af[t]  = *(const short8*)&sA[(wr * 64 + t * 16 + cl) * 32 + q * 8];
      bfr[t] = *(const short8*)&sB[(wc * 64 + t * 16 + cl) * 32 + q * 8];
    }
#pragma unroll
    for (int tm = 0; tm < 4; ++tm)
#pragma unroll
      for (int tn = 0; tn < 4; ++tn)
        acc[tm][tn] = __builtin_amdgcn_mfma_f32_16x16x32_bf16(af[tm], bfr[tn], acc[tm][tn], 0, 0, 0);
    __syncthreads();
  }

  // epilogue: C/D layout col=lane&15, row=quad*4+reg (verified m89/m91)
#pragma unroll
  for (int tm = 0; tm < 4; ++tm) {
#pragma unroll
    for (int tn = 0; tn < 4; ++tn) {
      const int col = colBlk + wc * 64 + tn * 16 + cl;
#pragma unroll
      for (int r = 0; r < 4; ++r) {
        const int row = rowBlk + wr * 64 + tm * 16 + q * 4 + r;
        float v = acc[tm][tn][r];
        if constexpr (EPI == 0) {
          float other = __shfl_xor(v, 1);   // partner col (col^1), same row
          if (col < 1280) {                 // Q (0..1023) and K (1024..1279) get RoPE
            int s = row & (SEQ - 1);
            int t = (col & 63) >> 1;
            float cv = fc[s * 32 + t], sv = fs[s * 32 + t];
            v = ((col & 1) == 0) ? (v * cv - other * sv) : (other * sv + v * cv);
          }
          outBF[(size_t)row * N + col] = f2bf(v);
        } else if constexpr (EPI == 1) {
          outF[(size_t)row * N + col] = v + aux1[col];
        } else if constexpr (EPI == 2) {
          int vr = (row >> 10) * 128 + ((row & (SEQ - 1)) >> 3);
          outF[(size_t)row * N + col] =
              aux1[(size_t)row * N + col] + aux2[(size_t)vr * 3072 + 2048 + col] * v;
        } else if constexpr (EPI == 3) {
          outBF[(size_t)row * N + col] = f2bf(v);
        } else if constexpr (EPI == 4) {
          int vr = (row >> 10) * 128 + ((row & (SEQ - 1)) >> 3);
          outF[(size_t)row * N + col] =
              aux1[(size_t)row * N + col] + aux2[(size_t)vr * 3072 + 2048 + col] * v;
        }
      }
    }
  }
}

// ---------------- rmsnorm + modulation -> bf16 ----------------
__global__ __launch_bounds__(256) void rms_mod(
    const float* __restrict__ X, const float* __restrict__ w,
    const float* __restrict__ mod, unsigned short* __restrict__ out)
{
  const int r = blockIdx.x;
  const int b = r >> 10, s = r & (SEQ - 1);
  const int vr = b * 128 + (s >> 3);
  const size_t base = (size_t)r * DIM;
  float v[4];
  float ss = 0.f;
#pragma unroll
  for (int p = 0; p < 4; ++p) {
    int c = threadIdx.x + p * 256;
    v[p] = X[base + c];
    ss += v[p] * v[p];
  }
#pragma unroll
  for (int off = 1; off < 64; off <<= 1) ss += __shfl_xor(ss, off);
  __shared__ float red[4];
  int lane = threadIdx.x & 63, wv = threadIdx.x >> 6;
  if (lane == 0) red[wv] = ss;
  __syncthreads();
  float total = red[0] + red[1] + red[2] + red[3];
  float rn = rsqrtf(total * (1.0f / 1024.0f) + 1e-6f);
  const float* mrow = mod + (size_t)vr * 3072;
#pragma unroll
  for (int p = 0; p < 4; ++p) {
    int c = threadIdx.x + p * 256;
    out[base + c] = f2bf(v[p] * rn * w[c] * (1.0f + mrow[1024 + c]) + mrow[c]);
  }
}

// ---------------- flash block-causal attention (fp32 VALU, bf16 I/O) ----------------
// QKV packed [4096][1536] bf16: q cols 0..1023, k 1024..1279, v 1280..1535
__global__ __launch_bounds__(256) void attn_kernel(
    const unsigned short* __restrict__ QKV, unsigned short* __restrict__ O)
{
  const int bid = blockIdx.x;
  const int qt = bid & 15;
  const int h = (bid >> 4) & 15;
  const int b = bid >> 8;
  const int kvh = h >> 2;
  __shared__ float Qs[64][65];
  __shared__ float Ks[64][65];  // reused for P after scores
  __shared__ float Vs[64][65];
  const int tid = threadIdx.x;
  const int tx = tid & 15, ty = tid >> 4;

  for (int idx = tid; idx < 64 * 64; idx += 256) {
    int i = idx >> 6, d = idx & 63;
    Qs[i][d] = bf2f(QKV[(size_t)(b * SEQ + qt * 64 + i) * 1536 + h * 64 + d]);
  }
  float acc[4][4] = {};
  float m_r[4], l_r[4];
#pragma unroll
  for (int m = 0; m < 4; ++m) { m_r[m] = -1e30f; l_r[m] = 0.f; }

  for (int kt = 0; kt <= qt; ++kt) {
    __syncthreads();
    for (int idx = tid; idx < 64 * 64; idx += 256) {
      int j = idx >> 6, d = idx & 63;
      size_t roff = (size_t)(b * SEQ + kt * 64 + j) * 1536;
      Ks[j][d] = bf2f(QKV[roff + 1024 + kvh * 64 + d]);
      Vs[j][d] = bf2f(QKV[roff + 1280 + kvh * 64 + d]);
    }
    __syncthreads();
    float s[4][4] = {};
    for (int d = 0; d < 64; ++d) {
      float a[4], kk[4];
#pragma unroll
      for (int m = 0; m < 4; ++m) a[m] = Qs[ty * 4 + m][d];
#pragma unroll
      for (int n = 0; n < 4; ++n) kk[n] = Ks[tx * 4 + n][d];
#pragma unroll
      for (int m = 0; m < 4; ++m)
#pragma unroll
        for (int n = 0; n < 4; ++n) s[m][n] = fmaf(a[m], kk[n], s[m][n]);
    }
#pragma unroll
    for (int m = 0; m < 4; ++m)
#pragma unroll
      for (int n = 0; n < 4; ++n) {
        float val = s[m][n] * 0.125f;
        if (kt == qt && ((tx * 4 + n) >> 3) > ((ty * 4 + m) >> 3)) val = -1e9f;
        s[m][n] = val;
      }
    float p[4][4], alpha[4];
#pragma unroll
    for (int m = 0; m < 4; ++m) {
      float rmax = fmaxf(fmaxf(s[m][0], s[m][1]), fmaxf(s[m][2], s[m][3]));
#pragma unroll
      for (int off = 1; off < 16; off <<= 1) rmax = fmaxf(rmax, __shfl_xor(rmax, off));
      float mnew = fmaxf(m_r[m], rmax);
      alpha[m] = expf(m_r[m] - mnew);
      float rsum = 0.f;
#pragma unroll
      for (int n = 0; n < 4; ++n) { p[m][n] = expf(s[m][n] - mnew); rsum += p[m][n]; }
#pragma unroll
      for (int off = 1; off < 16; off <<= 1) rsum += __shfl_xor(rsum, off);
      l_r[m] = l_r[m] * alpha[m] + rsum;
      m_r[m] = mnew;
    }
    __syncthreads();
#pragma unroll
    for (int m = 0; m < 4; ++m)
#pragma unroll
      for (int n = 0; n < 4; ++n) Ks[ty * 4 + m][tx * 4 + n] = p[m][n];
#pragma unroll
    for (int m = 0; m < 4; ++m)
#pragma unroll
      for (int n = 0; n < 4; ++n) acc[m][n] *= alpha[m];
    __syncthreads();
    for (int j = 0; j < 64; ++j) {
      float pm[4], vn[4];
#pragma unroll
      for (int m = 0; m < 4; ++m) pm[m] = Ks[ty * 4 + m][j];
#pragma unroll
      for (int n = 0; n < 4; ++n) vn[n] = Vs[j][tx * 4 + n];
#pragma unroll
      for (int m = 0; m < 4; ++m)
#pragma unroll
        for (int n = 0; n < 4; ++n) acc[m][n] = fmaf(pm[m], vn[n], acc[m][n]);
    }
  }
#pragma unroll
  for (int m = 0; m < 4; ++m) {
    float inv = 1.0f / l_r[m];
    unsigned short* o = O + (size_t)(b * SEQ + qt * 64 + ty * 4 + m) * DIM + h * 64 + tx * 4;
#pragma unroll
    for (int n = 0; n < 4; ++n) o[n] = f2bf(acc[m][n] * inv);
  }
}

// ---------------- swiglu: g = silu(u1)*u3 (bf16 in/out) ----------------
__global__ __launch_bounds__(256) void swiglu(const unsigned short* __restrict__ U,
                                              unsigned short* __restrict__ G)
{
  int gid = blockIdx.x * 256 + threadIdx.x;  // 4096*128 threads
  int row = gid >> 7;
  int col = (gid & 127) * 8;
  short8 u1 = *(const short8*)(U + (size_t)row * 2048 + col);
  short8 u3 = *(const short8*)(U + (size_t)row * 2048 + 1024 + col);
  short8 g;
#pragma unroll
  for (int j = 0; j < 8; ++j) {
    float f1 = bf2f((unsigned short)u1[j]);
    float f3 = bf2f((unsigned short)u3[j]);
    float s = f1 / (1.0f + expf(-f1)) * f3;
    g[j] = (short)f2bf(s);
  }
  *(short8*)(G + (size_t)row * 1024 + col) = g;
}

extern "C" void kernel_launch(void* const* d_in, const int* in_sizes, int n_in,
                              void* d_out, int out_size, void* d_ws, size_t ws_size,
                              hipStream_t stream)
{
  const float* x   = (const float*)d_in[0];
  const float* vec = (const float*)d_in[1];
  const float* wq  = (const float*)d_in[2];
  const float* wk  = (const float*)d_in[3];
  const float* wv  = (const float*)d_in[4];
  const float* wo  = (const float*)d_in[5];
  const float* w1  = (const float*)d_in[6];
  const float* w2  = (const float*)d_in[7];
  const float* w3  = (const float*)d_in[8];
  const float* maw = (const float*)d_in[9];
  const float* mab = (const float*)d_in[10];
  const float* mfw = (const float*)d_in[11];
  const float* mfb = (const float*)d_in[12];
  const float* n1w = (const float*)d_in[13];
  const float* n2w = (const float*)d_in[14];
  const float* fc  = (const float*)d_in[15];
  const float* fs  = (const float*)d_in[16];

  char* p = (char*)d_ws;
  auto takeU = [&](size_t elems) { unsigned short* r = (unsigned short*)p; p += elems * 2; return r; };
  auto takeF = [&](size_t elems) { float* r = (float*)p; p += elems * 4; return r; };

  unsigned short* WQKV = takeU((size_t)1536 * 1024);
  unsigned short* WOb  = takeU((size_t)1024 * 1024);
  unsigned short* W13  = takeU((size_t)2048 * 1024);
  unsigned short* W2b  = takeU((size_t)1024 * 1024);
  unsigned short* WMA  = takeU((size_t)3072 * 1024);
  unsigned short* WMF  = takeU((size_t)3072 * 1024);
  unsigned short* SVEC = takeU((size_t)512 * 1024);
  float* MODA = takeF((size_t)512 * 3072);
  float* MODF = takeF((size_t)512 * 3072);
  float* H    = takeF((size_t)4096 * 1024);
  unsigned short* XNb  = takeU((size_t)4096 * 1024);
  unsigned short* QKVb = takeU((size_t)4096 * 1536);
  unsigned short* AOb  = takeU((size_t)4096 * 1024);
  unsigned short* HNb  = takeU((size_t)4096 * 1024);
  // aliases over dead buffers (launch order is strictly sequential on stream):
  unsigned short* U13 = XNb;   // 4096*2048 bf16 fits in XNb+QKVb (dead after attn)
  unsigned short* Gb  = AOb;   // dead after WO gemm
  // total ws use ~92.3 MB

  dim3 blk(256);

  // 1) weight casts f32->bf16 (WQKV packs wq|wk|wv; W13 packs w1|w3)
  CastArgs ca;
  ca.src[0] = wq;  ca.dst[0] = WQKV;                    ca.n[0] = 1024 * 1024;
  ca.src[1] = wk;  ca.dst[1] = WQKV + 1024 * 1024;      ca.n[1] = 256 * 1024;
  ca.src[2] = wv;  ca.dst[2] = WQKV + 1280 * 1024;      ca.n[2] = 256 * 1024;
  ca.src[3] = wo;  ca.dst[3] = WOb;                     ca.n[3] = 1024 * 1024;
  ca.src[4] = w1;  ca.dst[4] = W13;                     ca.n[4] = 1024 * 1024;
  ca.src[5] = w3;  ca.dst[5] = W13 + 1024 * 1024;       ca.n[5] = 1024 * 1024;
  ca.src[6] = w2;  ca.dst[6] = W2b;                     ca.n[6] = 1024 * 1024;
  ca.src[7] = maw; ca.dst[7] = WMA;                     ca.n[7] = 3072 * 1024;
  ca.src[8] = mfw; ca.dst[8] = WMF;                     ca.n[8] = 3072 * 1024;
  cast_weights<<<dim3(3072, 9), blk, 0, stream>>>(ca);

  // 2) silu(vec) -> bf16
  silu_cast<<<512, blk, 0, stream>>>(vec, SVEC, 512 * 1024);

  // 3) modulation GEMMs -> f32
  mfma_gemm<1><<<dim3(24, 4), blk, 0, stream>>>(SVEC, WMA, 512, 3072, 1024,
      MODA, nullptr, mab, nullptr, nullptr, nullptr);
  mfma_gemm<1><<<dim3(24, 4), blk, 0, stream>>>(SVEC, WMF, 512, 3072, 1024,
      MODF, nullptr, mfb, nullptr, nullptr, nullptr);

  // 4) xn = rmsnorm(x)*(1+sc_a)+sh_a -> bf16
  rms_mod<<<4096, blk, 0, stream>>>(x, n1w, MODA, XNb);

  // 5) fused QKV GEMM + RoPE -> packed bf16 [4096,1536]
  mfma_gemm<0><<<dim3(12, 32), blk, 0, stream>>>(XNb, WQKV, 4096, 1536, 1024,
      nullptr, QKVb, nullptr, nullptr, fc, fs);

  // 6) attention -> AO bf16
  attn_kernel<<<1024, blk, 0, stream>>>(QKVb, AOb);

  // 7) h = x + gate_a * (AO @ wo^T) -> f32
  mfma_gemm<2><<<dim3(8, 32), blk, 0, stream>>>(AOb, WOb, 4096, 1024, 1024,
      H, nullptr, x, MODA, nullptr, nullptr);

  // 8) hn = rmsnorm(h)*(1+sc_f)+sh_f -> bf16
  rms_mod<<<4096, blk, 0, stream>>>(H, n2w, MODF, HNb);

  // 9) u13 = hn @ [w1|w3]^T -> bf16 [4096,2048]
  mfma_gemm<3><<<dim3(16, 32), blk, 0, stream>>>(HNb, W13, 4096, 2048, 1024,
      nullptr, U13, nullptr, nullptr, nullptr, nullptr);

  // 10) g = silu(u1)*u3 -> bf16
  swiglu<<<2048, blk, 0, stream>>>(U13, Gb);

  // 11) out = h + gate_f * (g @ w2^T) -> f32
  mfma_gemm<4><<<dim3(8, 32), blk, 0, stream>>>(Gb, W2b, 4096, 1024, 1024,
      (float*)d_out, nullptr, H, MODF, nullptr, nullptr);
}

// Round 4
// 439.063 us; speedup vs baseline: 3.8665x; 1.6274x over previous
//
#include <hip/hip_runtime.h>
#include <math.h>

// B=4, S=1024, D=1024, H=16, KVH=4, HD=64, HIDDEN=1024, BLK=8
#define SEQ 1024
#define DIM 1024

using short8 = __attribute__((ext_vector_type(8))) short;
using f32x4  = __attribute__((ext_vector_type(4))) float;

__device__ __forceinline__ unsigned short f2bf(float f) {
  unsigned int u = __float_as_uint(f);
  u = (u + 0x7FFFu + ((u >> 16) & 1u)) >> 16;
  return (unsigned short)u;
}
__device__ __forceinline__ float bf2f(unsigned short h) {
  return __uint_as_float(((unsigned int)h) << 16);
}
__device__ __forceinline__ void load16_lds(const unsigned short* g, unsigned short* l) {
  __builtin_amdgcn_global_load_lds((const __attribute__((address_space(1))) void*)g,
                                   (__attribute__((address_space(3))) void*)l, 16, 0, 0);
}

// ---------------- weight cast (f32 -> bf16), 9 regions ----------------
struct CastArgs {
  const float* src[9];
  unsigned short* dst[9];
  int n[9];
};
__global__ __launch_bounds__(256) void cast_weights(CastArgs a) {
  int r = blockIdx.y;
  int i4 = (blockIdx.x * 256 + threadIdx.x) * 4;
  if (i4 >= a.n[r]) return;
  const float4 v = *(const float4*)(a.src[r] + i4);
  ushort4 o;
  o.x = f2bf(v.x); o.y = f2bf(v.y); o.z = f2bf(v.z); o.w = f2bf(v.w);
  *(ushort4*)(a.dst[r] + i4) = o;
}

// ---------------- silu(vec) -> bf16 ----------------
__global__ __launch_bounds__(256) void silu_cast(const float* __restrict__ v,
                                                 unsigned short* __restrict__ o, int n) {
  int i4 = (blockIdx.x * 256 + threadIdx.x) * 4;
  if (i4 >= n) return;
  float4 x = *(const float4*)(v + i4);
  ushort4 r;
  r.x = f2bf(x.x / (1.0f + expf(-x.x)));
  r.y = f2bf(x.y / (1.0f + expf(-x.y)));
  r.z = f2bf(x.z / (1.0f + expf(-x.z)));
  r.w = f2bf(x.w / (1.0f + expf(-x.w)));
  *(ushort4*)(o + i4) = r;
}

// ---------------- MFMA GEMM: C[M,N] = A[M,K] @ W[N,K]^T (A,W bf16) ----------------
// 128x128 block tile, 4 waves (2x2) each 64x64, BK=32, global_load_lds width 16.
// EPI: 0 QKV(+RoPE)->bf16[N=1536]  1 +bias->f32  2 x+gate*acc->f32 (h)
//      3 plain->bf16               4 h+gate*acc->f32 (final)
template<int EPI>
__global__ __launch_bounds__(256) void mfma_gemm(
    const unsigned short* __restrict__ A, const unsigned short* __restrict__ W,
    int M, int N, int K,
    float* __restrict__ outF, unsigned short* __restrict__ outBF,
    const float* __restrict__ aux1,   // bias / xres / hres
    const float* __restrict__ aux2,   // mod base (gate at +2048)
    const float* __restrict__ fc, const float* __restrict__ fs)
{
  __shared__ unsigned short sA[128 * 32];
  __shared__ unsigned short sB[128 * 32];
  const int tid = threadIdx.x;
  const int lane = tid & 63;
  const int wv = tid >> 6;          // 0..3
  const int wr = wv >> 1, wc = wv & 1;
  const int rowBlk = blockIdx.y * 128;
  const int colBlk = blockIdx.x * 128;
  const int l4 = lane >> 2;         // row within 16-row chunk
  const int lk = (lane & 3) * 8;    // k element offset (8 bf16 = 16B)
  const int q = lane >> 4;          // quad
  const int cl = lane & 15;

  f32x4 acc[4][4] = {};

  for (int k0 = 0; k0 < K; k0 += 32) {
#pragma unroll
    for (int c = 0; c < 2; ++c) {
      int ch = wv * 2 + c;          // chunk 0..7 (16 rows each)
      int row = ch * 16 + l4;
      load16_lds(A + (size_t)(rowBlk + row) * K + k0 + lk, &sA[ch * 512 + lane * 8]);
      load16_lds(W + (size_t)(colBlk + row) * K + k0 + lk, &sB[ch * 512 + lane * 8]);
    }
    __syncthreads();
    short8 af[4], bfr[4];
#pragma unroll
    for (int t = 0; t < 4; ++t) {
      af[t]  = *(const short8*)&sA[(wr * 64 + t * 16 + cl) * 32 + q * 8];
      bfr[t] = *(const short8*)&sB[(wc * 64 + t * 16 + cl) * 32 + q * 8];
    }
#pragma unroll
    for (int tm = 0; tm < 4; ++tm)
#pragma unroll
      for (int tn = 0; tn < 4; ++tn)
        acc[tm][tn] = __builtin_amdgcn_mfma_f32_16x16x32_bf16(af[tm], bfr[tn], acc[tm][tn], 0, 0, 0);
    __syncthreads();
  }

  // epilogue: C/D layout col=lane&15, row=quad*4+reg (verified m89/m91)
#pragma unroll
  for (int tm = 0; tm < 4; ++tm) {
#pragma unroll
    for (int tn = 0; tn < 4; ++tn) {
      const int col = colBlk + wc * 64 + tn * 16 + cl;
#pragma unroll
      for (int r = 0; r < 4; ++r) {
        const int row = rowBlk + wr * 64 + tm * 16 + q * 4 + r;
        float v = acc[tm][tn][r];
        if constexpr (EPI == 0) {
          float other = __shfl_xor(v, 1);   // partner col (col^1), same row
          if (col < 1280) {                 // Q (0..1023) and K (1024..1279) get RoPE
            int s = row & (SEQ - 1);
            int t = (col & 63) >> 1;
            float cv = fc[s * 32 + t], sv = fs[s * 32 + t];
            v = ((col & 1) == 0) ? (v * cv - other * sv) : (other * sv + v * cv);
          }
          outBF[(size_t)row * N + col] = f2bf(v);
        } else if constexpr (EPI == 1) {
          outF[(size_t)row * N + col] = v + aux1[col];
        } else if constexpr (EPI == 2) {
          int vr = (row >> 10) * 128 + ((row & (SEQ - 1)) >> 3);
          outF[(size_t)row * N + col] =
              aux1[(size_t)row * N + col] + aux2[(size_t)vr * 3072 + 2048 + col] * v;
        } else if constexpr (EPI == 3) {
          outBF[(size_t)row * N + col] = f2bf(v);
        } else if constexpr (EPI == 4) {
          int vr = (row >> 10) * 128 + ((row & (SEQ - 1)) >> 3);
          outF[(size_t)row * N + col] =
              aux1[(size_t)row * N + col] + aux2[(size_t)vr * 3072 + 2048 + col] * v;
        }
      }
    }
  }
}

// ---------------- rmsnorm + modulation -> bf16 ----------------
__global__ __launch_bounds__(256) void rms_mod(
    const float* __restrict__ X, const float* __restrict__ w,
    const float* __restrict__ mod, unsigned short* __restrict__ out)
{
  const int r = blockIdx.x;
  const int b = r >> 10, s = r & (SEQ - 1);
  const int vr = b * 128 + (s >> 3);
  const size_t base = (size_t)r * DIM;
  float v[4];
  float ss = 0.f;
#pragma unroll
  for (int p = 0; p < 4; ++p) {
    int c = threadIdx.x + p * 256;
    v[p] = X[base + c];
    ss += v[p] * v[p];
  }
#pragma unroll
  for (int off = 1; off < 64; off <<= 1) ss += __shfl_xor(ss, off);
  __shared__ float red[4];
  int lane = threadIdx.x & 63, wv = threadIdx.x >> 6;
  if (lane == 0) red[wv] = ss;
  __syncthreads();
  float total = red[0] + red[1] + red[2] + red[3];
  float rn = rsqrtf(total * (1.0f / 1024.0f) + 1e-6f);
  const float* mrow = mod + (size_t)vr * 3072;
#pragma unroll
  for (int p = 0; p < 4; ++p) {
    int c = threadIdx.x + p * 256;
    out[base + c] = f2bf(v[p] * rn * w[c] * (1.0f + mrow[1024 + c]) + mrow[c]);
  }
}

// ---------------- MFMA flash block-causal attention ----------------
// QKV packed [4096][1536] bf16: q cols 0..1023, k 1024..1279, v 1280..1535
// One block per (b, h, q-tile of 64). 4 waves, each owns 16 q rows.
__global__ __launch_bounds__(256) void attn_mfma(
    const unsigned short* __restrict__ QKV, unsigned short* __restrict__ O)
{
  const int bid = blockIdx.x;
  const int qt = bid & 15;
  const int h = (bid >> 4) & 15;
  const int b = bid >> 8;
  const int kvh = h >> 2;
  __shared__ unsigned short sK[64 * 64];      // [key][d], d XOR-swizzled by (key&7)*8
  __shared__ unsigned short sVt[64 * 72];     // [d][key], +8 pad
  __shared__ unsigned short sP[4][16 * 72];   // per-wave P strip [qrow][key], +8 pad
  const int tid = threadIdx.x;
  const int lane = tid & 63;
  const int w = tid >> 6;       // wave = q-row strip
  const int q = lane >> 4;      // quad
  const int cl = lane & 15;

  // Q fragments: rows w*16+cl, k = s*32 + q*8 .. +8 (A-operand layout), kept in regs
  short8 qf[2];
  {
    const size_t qrow = (size_t)(b * SEQ + qt * 64 + w * 16 + cl) * 1536 + h * 64;
#pragma unroll
    for (int s = 0; s < 2; ++s)
      qf[s] = *(const short8*)(QKV + qrow + s * 32 + q * 8);
  }

  f32x4 accO[4] = {};           // 4 d-tiles x (4 rows/lane), C-layout rows q*4+r
  float m_r[4], l_r[4];
#pragma unroll
  for (int r = 0; r < 4; ++r) { m_r[r] = -1e30f; l_r[r] = 0.f; }

  for (int kt = 0; kt <= qt; ++kt) {
    __syncthreads();
    // ---- stage K (swizzled) ----
    {
      int rr = tid >> 3;            // 0..31
      int d0 = (tid & 7) * 8;
#pragma unroll
      for (int ppp = 0; ppp < 2; ++ppp) {
        int key = ppp * 32 + rr;
        const unsigned short* g =
            QKV + (size_t)(b * SEQ + kt * 64 + key) * 1536 + 1024 + kvh * 64 + d0;
        short8 kv = *(const short8*)g;
        *(short8*)(sK + key * 64 + (d0 ^ ((key & 7) * 8))) = kv;
      }
      // ---- stage V transposed: Vt[d][key] ----
      int d = tid & 63;
      int kg = tid >> 6;            // == wave id, uniform per wave
#pragma unroll
      for (int ppp = 0; ppp < 2; ++ppp) {
        int key0 = ppp * 32 + kg * 8;
        unsigned short tmp[8];
#pragma unroll
        for (int j = 0; j < 8; ++j)
          tmp[j] = QKV[(size_t)(b * SEQ + kt * 64 + key0 + j) * 1536 + 1280 + kvh * 64 + d];
        *(short8*)(sVt + d * 72 + key0) = *(const short8*)tmp;
      }
    }
    __syncthreads();

    // ---- S = Q K^T (16 q rows x 64 keys per wave) ----
    f32x4 accS[4] = {};
#pragma unroll
    for (int s = 0; s < 2; ++s) {
#pragma unroll
      for (int n = 0; n < 4; ++n) {
        int rowk = n * 16 + cl;
        short8 kf = *(const short8*)(sK + rowk * 64 + ((s * 32 + q * 8) ^ ((cl & 7) * 8)));
        accS[n] = __builtin_amdgcn_mfma_f32_16x16x32_bf16(qf[s], kf, accS[n], 0, 0, 0);
      }
    }

    // ---- scale + block-causal mask ----
    // C row = q*4+r; (q*4+r)>>3 == q>>1 (r<4), so mask is uniform over r.
    float sv[4][4];
    const bool diag = (kt == qt);
    const int qblk = w * 2 + (q >> 1);
#pragma unroll
    for (int n = 0; n < 4; ++n) {
      const bool msk = diag && (n * 2 + (cl >> 3)) > qblk;
#pragma unroll
      for (int r = 0; r < 4; ++r)
        sv[n][r] = msk ? -1e30f : accS[n][r] * 0.125f;
    }

    // ---- online softmax (row stats across 16 lanes of quad) ----
    float alpha[4];
#pragma unroll
    for (int r = 0; r < 4; ++r) {
      float vmax = fmaxf(fmaxf(sv[0][r], sv[1][r]), fmaxf(sv[2][r], sv[3][r]));
      vmax = fmaxf(vmax, __shfl_xor(vmax, 1));
      vmax = fmaxf(vmax, __shfl_xor(vmax, 2));
      vmax = fmaxf(vmax, __shfl_xor(vmax, 4));
      vmax = fmaxf(vmax, __shfl_xor(vmax, 8));
      float mnew = fmaxf(m_r[r], vmax);
      alpha[r] = expf(m_r[r] - mnew);
      float rs = 0.f;
#pragma unroll
      for (int n = 0; n < 4; ++n) {
        float pp = expf(sv[n][r] - mnew);
        sv[n][r] = pp;
        rs += pp;
      }
      rs += __shfl_xor(rs, 1);
      rs += __shfl_xor(rs, 2);
      rs += __shfl_xor(rs, 4);
      rs += __shfl_xor(rs, 8);
      l_r[r] = l_r[r] * alpha[r] + rs;
      m_r[r] = mnew;
    }

    // ---- P -> LDS (per-wave region, no block sync needed) ----
#pragma unroll
    for (int n = 0; n < 4; ++n)
#pragma unroll
      for (int r = 0; r < 4; ++r)
        sP[w][(q * 4 + r) * 72 + n * 16 + cl] = f2bf(sv[n][r]);

    // ---- rescale O ----
#pragma unroll
    for (int dn = 0; dn < 4; ++dn) {
      accO[dn][0] *= alpha[0];
      accO[dn][1] *= alpha[1];
      accO[dn][2] *= alpha[2];
      accO[dn][3] *= alpha[3];
    }

    // ---- O += P V ----
    short8 pf[2];
    pf[0] = *(const short8*)(&sP[w][cl * 72 + q * 8]);
    pf[1] = *(const short8*)(&sP[w][cl * 72 + 32 + q * 8]);
#pragma unroll
    for (int dn = 0; dn < 4; ++dn) {
#pragma unroll
      for (int s = 0; s < 2; ++s) {
        short8 vf = *(const short8*)(sVt + (dn * 16 + cl) * 72 + s * 32 + q * 8);
        accO[dn] = __builtin_amdgcn_mfma_f32_16x16x32_bf16(pf[s], vf, accO[dn], 0, 0, 0);
      }
    }
  }

  // ---- epilogue: O / l -> bf16 ----
  float invl[4];
#pragma unroll
  for (int r = 0; r < 4; ++r) invl[r] = 1.0f / l_r[r];
#pragma unroll
  for (int dn = 0; dn < 4; ++dn)
#pragma unroll
    for (int r = 0; r < 4; ++r) {
      int row = b * SEQ + qt * 64 + w * 16 + q * 4 + r;
      O[(size_t)row * DIM + h * 64 + dn * 16 + cl] = f2bf(accO[dn][r] * invl[r]);
    }
}

// ---------------- swiglu: g = silu(u1)*u3 (bf16 in/out) ----------------
__global__ __launch_bounds__(256) void swiglu(const unsigned short* __restrict__ U,
                                              unsigned short* __restrict__ G)
{
  int gid = blockIdx.x * 256 + threadIdx.x;  // 4096*128 threads
  int row = gid >> 7;
  int col = (gid & 127) * 8;
  short8 u1 = *(const short8*)(U + (size_t)row * 2048 + col);
  short8 u3 = *(const short8*)(U + (size_t)row * 2048 + 1024 + col);
  short8 g;
#pragma unroll
  for (int j = 0; j < 8; ++j) {
    float f1 = bf2f((unsigned short)u1[j]);
    float f3 = bf2f((unsigned short)u3[j]);
    float s = f1 / (1.0f + expf(-f1)) * f3;
    g[j] = (short)f2bf(s);
  }
  *(short8*)(G + (size_t)row * 1024 + col) = g;
}

extern "C" void kernel_launch(void* const* d_in, const int* in_sizes, int n_in,
                              void* d_out, int out_size, void* d_ws, size_t ws_size,
                              hipStream_t stream)
{
  const float* x   = (const float*)d_in[0];
  const float* vec = (const float*)d_in[1];
  const float* wq  = (const float*)d_in[2];
  const float* wk  = (const float*)d_in[3];
  const float* wv  = (const float*)d_in[4];
  const float* wo  = (const float*)d_in[5];
  const float* w1  = (const float*)d_in[6];
  const float* w2  = (const float*)d_in[7];
  const float* w3  = (const float*)d_in[8];
  const float* maw = (const float*)d_in[9];
  const float* mab = (const float*)d_in[10];
  const float* mfw = (const float*)d_in[11];
  const float* mfb = (const float*)d_in[12];
  const float* n1w = (const float*)d_in[13];
  const float* n2w = (const float*)d_in[14];
  const float* fc  = (const float*)d_in[15];
  const float* fs  = (const float*)d_in[16];

  char* p = (char*)d_ws;
  auto takeU = [&](size_t elems) { unsigned short* r = (unsigned short*)p; p += elems * 2; return r; };
  auto takeF = [&](size_t elems) { float* r = (float*)p; p += elems * 4; return r; };

  unsigned short* WQKV = takeU((size_t)1536 * 1024);
  unsigned short* WOb  = takeU((size_t)1024 * 1024);
  unsigned short* W13  = takeU((size_t)2048 * 1024);
  unsigned short* W2b  = takeU((size_t)1024 * 1024);
  unsigned short* WMA  = takeU((size_t)3072 * 1024);
  unsigned short* WMF  = takeU((size_t)3072 * 1024);
  unsigned short* SVEC = takeU((size_t)512 * 1024);
  float* MODA = takeF((size_t)512 * 3072);
  float* MODF = takeF((size_t)512 * 3072);
  float* H    = takeF((size_t)4096 * 1024);
  unsigned short* XNb  = takeU((size_t)4096 * 1024);
  unsigned short* QKVb = takeU((size_t)4096 * 1536);
  unsigned short* AOb  = takeU((size_t)4096 * 1024);
  unsigned short* HNb  = takeU((size_t)4096 * 1024);
  // aliases over dead buffers (launch order is strictly sequential on stream):
  unsigned short* U13 = XNb;   // 4096*2048 bf16 fits in XNb+QKVb (dead after attn)
  unsigned short* Gb  = AOb;   // dead after WO gemm

  dim3 blk(256);

  // 1) weight casts f32->bf16 (WQKV packs wq|wk|wv; W13 packs w1|w3)
  CastArgs ca;
  ca.src[0] = wq;  ca.dst[0] = WQKV;                    ca.n[0] = 1024 * 1024;
  ca.src[1] = wk;  ca.dst[1] = WQKV + 1024 * 1024;      ca.n[1] = 256 * 1024;
  ca.src[2] = wv;  ca.dst[2] = WQKV + 1280 * 1024;      ca.n[2] = 256 * 1024;
  ca.src[3] = wo;  ca.dst[3] = WOb;                     ca.n[3] = 1024 * 1024;
  ca.src[4] = w1;  ca.dst[4] = W13;                     ca.n[4] = 1024 * 1024;
  ca.src[5] = w3;  ca.dst[5] = W13 + 1024 * 1024;       ca.n[5] = 1024 * 1024;
  ca.src[6] = w2;  ca.dst[6] = W2b;                     ca.n[6] = 1024 * 1024;
  ca.src[7] = maw; ca.dst[7] = WMA;                     ca.n[7] = 3072 * 1024;
  ca.src[8] = mfw; ca.dst[8] = WMF;                     ca.n[8] = 3072 * 1024;
  cast_weights<<<dim3(3072, 9), blk, 0, stream>>>(ca);

  // 2) silu(vec) -> bf16
  silu_cast<<<512, blk, 0, stream>>>(vec, SVEC, 512 * 1024);

  // 3) modulation GEMMs -> f32
  mfma_gemm<1><<<dim3(24, 4), blk, 0, stream>>>(SVEC, WMA, 512, 3072, 1024,
      MODA, nullptr, mab, nullptr, nullptr, nullptr);
  mfma_gemm<1><<<dim3(24, 4), blk, 0, stream>>>(SVEC, WMF, 512, 3072, 1024,
      MODF, nullptr, mfb, nullptr, nullptr, nullptr);

  // 4) xn = rmsnorm(x)*(1+sc_a)+sh_a -> bf16
  rms_mod<<<4096, blk, 0, stream>>>(x, n1w, MODA, XNb);

  // 5) fused QKV GEMM + RoPE -> packed bf16 [4096,1536]
  mfma_gemm<0><<<dim3(12, 32), blk, 0, stream>>>(XNb, WQKV, 4096, 1536, 1024,
      nullptr, QKVb, nullptr, nullptr, fc, fs);

  // 6) MFMA flash attention -> AO bf16
  attn_mfma<<<1024, blk, 0, stream>>>(QKVb, AOb);

  // 7) h = x + gate_a * (AO @ wo^T) -> f32
  mfma_gemm<2><<<dim3(8, 32), blk, 0, stream>>>(AOb, WOb, 4096, 1024, 1024,
      H, nullptr, x, MODA, nullptr, nullptr);

  // 8) hn = rmsnorm(h)*(1+sc_f)+sh_f -> bf16
  rms_mod<<<4096, blk, 0, stream>>>(H, n2w, MODF, HNb);

  // 9) u13 = hn @ [w1|w3]^T -> bf16 [4096,2048]
  mfma_gemm<3><<<dim3(16, 32), blk, 0, stream>>>(HNb, W13, 4096, 2048, 1024,
      nullptr, U13, nullptr, nullptr, nullptr, nullptr);

  // 10) g = silu(u1)*u3 -> bf16
  swiglu<<<2048, blk, 0, stream>>>(U13, Gb);

  // 11) out = h + gate_f * (g @ w2^T) -> f32
  mfma_gemm<4><<<dim3(8, 32), blk, 0, stream>>>(Gb, W2b, 4096, 1024, 1024,
      (float*)d_out, nullptr, H, MODF, nullptr, nullptr);
}

// Round 5
// 366.619 us; speedup vs baseline: 4.6305x; 1.1976x over previous
//
#include <hip/hip_runtime.h>
#include <math.h>

// B=4, S=1024, D=1024, H=16, KVH=4, HD=64, HIDDEN=1024, BLK=8
#define SEQ 1024
#define DIM 1024

using short8 = __attribute__((ext_vector_type(8))) short;
using f32x4  = __attribute__((ext_vector_type(4))) float;

__device__ __forceinline__ unsigned short f2bf(float f) {
  unsigned int u = __float_as_uint(f);
  u = (u + 0x7FFFu + ((u >> 16) & 1u)) >> 16;
  return (unsigned short)u;
}
__device__ __forceinline__ float bf2f(unsigned short h) {
  return __uint_as_float(((unsigned int)h) << 16);
}
__device__ __forceinline__ void load16_lds(const unsigned short* g, unsigned short* l) {
  __builtin_amdgcn_global_load_lds((const __attribute__((address_space(1))) void*)g,
                                   (__attribute__((address_space(3))) void*)l, 16, 0, 0);
}

// ---------------- weight cast (f32 -> bf16), 9 regions ----------------
struct CastArgs {
  const float* src[9];
  unsigned short* dst[9];
  int n[9];
};
__global__ __launch_bounds__(256) void cast_weights(CastArgs a) {
  int r = blockIdx.y;
  int i4 = (blockIdx.x * 256 + threadIdx.x) * 4;
  if (i4 >= a.n[r]) return;
  const float4 v = *(const float4*)(a.src[r] + i4);
  ushort4 o;
  o.x = f2bf(v.x); o.y = f2bf(v.y); o.z = f2bf(v.z); o.w = f2bf(v.w);
  *(ushort4*)(a.dst[r] + i4) = o;
}

// ---------------- silu(vec) -> bf16 ----------------
__global__ __launch_bounds__(256) void silu_cast(const float* __restrict__ v,
                                                 unsigned short* __restrict__ o, int n) {
  int i4 = (blockIdx.x * 256 + threadIdx.x) * 4;
  if (i4 >= n) return;
  float4 x = *(const float4*)(v + i4);
  ushort4 r;
  r.x = f2bf(x.x / (1.0f + expf(-x.x)));
  r.y = f2bf(x.y / (1.0f + expf(-x.y)));
  r.z = f2bf(x.z / (1.0f + expf(-x.z)));
  r.w = f2bf(x.w / (1.0f + expf(-x.w)));
  *(ushort4*)(o + i4) = r;
}

// ---------------- MFMA GEMM: C[M,N] = A[M,K] @ W[N,K]^T (A,W bf16) ----------------
// 128x128 block tile, 4 waves (2x2) each 64x64, BK=32, global_load_lds width 16.
// EPI: 0 QKV(+RoPE)->bf16[N=1536]  1 +dual-bias->f32 (mod, N=6144)
//      2 x+gate*acc->f32 (h)       3 plain->bf16     4 h+gate*acc->f32 (final)
// MOD buffer row stride is 6144; gate pointer passed pre-offset.
template<int EPI>
__global__ __launch_bounds__(256) void mfma_gemm(
    const unsigned short* __restrict__ A, const unsigned short* __restrict__ W,
    int M, int N, int K,
    float* __restrict__ outF, unsigned short* __restrict__ outBF,
    const float* __restrict__ aux1,   // bias1 / xres / hres
    const float* __restrict__ aux2,   // bias2 / mod-gate base (stride 6144)
    const float* __restrict__ fc, const float* __restrict__ fs)
{
  __shared__ unsigned short sA[128 * 32];
  __shared__ unsigned short sB[128 * 32];
  const int tid = threadIdx.x;
  const int lane = tid & 63;
  const int wv = tid >> 6;          // 0..3
  const int wr = wv >> 1, wc = wv & 1;
  const int rowBlk = blockIdx.y * 128;
  const int colBlk = blockIdx.x * 128;
  const int l4 = lane >> 2;         // row within 16-row chunk
  const int lk = (lane & 3) * 8;    // k element offset (8 bf16 = 16B)
  const int q = lane >> 4;          // quad
  const int cl = lane & 15;

  f32x4 acc[4][4] = {};

  for (int k0 = 0; k0 < K; k0 += 32) {
#pragma unroll
    for (int c = 0; c < 2; ++c) {
      int ch = wv * 2 + c;          // chunk 0..7 (16 rows each)
      int row = ch * 16 + l4;
      load16_lds(A + (size_t)(rowBlk + row) * K + k0 + lk, &sA[ch * 512 + lane * 8]);
      load16_lds(W + (size_t)(colBlk + row) * K + k0 + lk, &sB[ch * 512 + lane * 8]);
    }
    __syncthreads();
    short8 af[4], bfr[4];
#pragma unroll
    for (int t = 0; t < 4; ++t) {
      af[t]  = *(const short8*)&sA[(wr * 64 + t * 16 + cl) * 32 + q * 8];
      bfr[t] = *(const short8*)&sB[(wc * 64 + t * 16 + cl) * 32 + q * 8];
    }
#pragma unroll
    for (int tm = 0; tm < 4; ++tm)
#pragma unroll
      for (int tn = 0; tn < 4; ++tn)
        acc[tm][tn] = __builtin_amdgcn_mfma_f32_16x16x32_bf16(af[tm], bfr[tn], acc[tm][tn], 0, 0, 0);
    __syncthreads();
  }

  // epilogue: C/D layout col=lane&15, row=quad*4+reg (verified m89/m91)
#pragma unroll
  for (int tm = 0; tm < 4; ++tm) {
#pragma unroll
    for (int tn = 0; tn < 4; ++tn) {
      const int col = colBlk + wc * 64 + tn * 16 + cl;
#pragma unroll
      for (int r = 0; r < 4; ++r) {
        const int row = rowBlk + wr * 64 + tm * 16 + q * 4 + r;
        float v = acc[tm][tn][r];
        if constexpr (EPI == 0) {
          float other = __shfl_xor(v, 1);   // partner col (col^1), same row
          if (col < 1280) {                 // Q (0..1023) and K (1024..1279) get RoPE
            int s = row & (SEQ - 1);
            int t = (col & 63) >> 1;
            float cv = fc[s * 32 + t], sv = fs[s * 32 + t];
            v = ((col & 1) == 0) ? (v * cv - other * sv) : (other * sv + v * cv);
          }
          outBF[(size_t)row * N + col] = f2bf(v);
        } else if constexpr (EPI == 1) {
          float bb = (col < 3072) ? aux1[col] : aux2[col - 3072];
          outF[(size_t)row * N + col] = v + bb;
        } else if constexpr (EPI == 2 || EPI == 4) {
          int vr = (row >> 10) * 128 + ((row & (SEQ - 1)) >> 3);
          outF[(size_t)row * N + col] =
              aux1[(size_t)row * N + col] + aux2[(size_t)vr * 6144 + col] * v;
        } else if constexpr (EPI == 3) {
          outBF[(size_t)row * N + col] = f2bf(v);
        }
      }
    }
  }
}

// ---------------- rmsnorm + modulation -> bf16 ----------------
// mod row stride 6144; off = 0 (attn: shift@0, scale@1024) or 3072 (ffn)
__global__ __launch_bounds__(256) void rms_mod(
    const float* __restrict__ X, const float* __restrict__ w,
    const float* __restrict__ mod, int off, unsigned short* __restrict__ out)
{
  const int r = blockIdx.x;
  const int b = r >> 10, s = r & (SEQ - 1);
  const int vr = b * 128 + (s >> 3);
  const size_t base = (size_t)r * DIM;
  float v[4];
  float ss = 0.f;
#pragma unroll
  for (int p = 0; p < 4; ++p) {
    int c = threadIdx.x + p * 256;
    v[p] = X[base + c];
    ss += v[p] * v[p];
  }
#pragma unroll
  for (int o = 1; o < 64; o <<= 1) ss += __shfl_xor(ss, o);
  __shared__ float red[4];
  int lane = threadIdx.x & 63, wvv = threadIdx.x >> 6;
  if (lane == 0) red[wvv] = ss;
  __syncthreads();
  float total = red[0] + red[1] + red[2] + red[3];
  float rn = rsqrtf(total * (1.0f / 1024.0f) + 1e-6f);
  const float* mrow = mod + (size_t)vr * 6144 + off;
#pragma unroll
  for (int p = 0; p < 4; ++p) {
    int c = threadIdx.x + p * 256;
    out[base + c] = f2bf(v[p] * rn * w[c] * (1.0f + mrow[1024 + c]) + mrow[c]);
  }
}

// ---------------- MFMA flash block-causal attention (balanced) ----------------
// QKV packed [4096][1536] bf16: q 0..1023, k 1024..1279, v 1280..1535
// Grid 512: (b, h, qpair). Each block processes q-tiles {pr, 15-pr} -> 17 KV iters
// for every block (perfect balance; fixes the qt==bid&15 same-CU pathology of R4).
__global__ __launch_bounds__(256) void attn_mfma(
    const unsigned short* __restrict__ QKV, unsigned short* __restrict__ O)
{
  const int bid = blockIdx.x;
  const int pr = bid & 7;
  const int h = (bid >> 3) & 15;
  const int b = bid >> 7;
  const int kvh = h >> 2;
  __shared__ unsigned short sK[64 * 64];      // [key][d], d XOR-swizzled by (key&7)*8
  __shared__ unsigned short sVt[64 * 72];     // [d][key], +8 pad
  __shared__ unsigned short sP[4][16 * 72];   // per-wave P strip [qrow][key], +8 pad
  const int tid = threadIdx.x;
  const int lane = tid & 63;
  const int w = tid >> 6;       // wave = q-row strip
  const int q = lane >> 4;      // quad
  const int cl = lane & 15;
  // softmax in log2 domain: p = 2^(s*SCL - m2)
  const float SCL = 0.125f * 1.44269504f;

  for (int ph = 0; ph < 2; ++ph) {
    const int qt = ph ? (15 - pr) : pr;

    // Q fragments: rows w*16+cl, k = s*32 + q*8 (A-operand layout), kept in regs
    short8 qf[2];
    {
      const size_t qrow = (size_t)(b * SEQ + qt * 64 + w * 16 + cl) * 1536 + h * 64;
#pragma unroll
      for (int s = 0; s < 2; ++s)
        qf[s] = *(const short8*)(QKV + qrow + s * 32 + q * 8);
    }

    f32x4 accO[4] = {};           // 4 d-tiles x (4 rows/lane), C-layout rows q*4+r
    float m_r[4], l_r[4];
#pragma unroll
    for (int r = 0; r < 4; ++r) { m_r[r] = -1e30f; l_r[r] = 0.f; }

    for (int kt = 0; kt <= qt; ++kt) {
      __syncthreads();
      // ---- stage K (swizzled) ----
      {
        int rr = tid >> 3;            // 0..31
        int d0 = (tid & 7) * 8;
#pragma unroll
        for (int ppp = 0; ppp < 2; ++ppp) {
          int key = ppp * 32 + rr;
          const unsigned short* g =
              QKV + (size_t)(b * SEQ + kt * 64 + key) * 1536 + 1024 + kvh * 64 + d0;
          short8 kv = *(const short8*)g;
          *(short8*)(sK + key * 64 + (d0 ^ ((key & 7) * 8))) = kv;
        }
        // ---- stage V transposed: Vt[d][key] (coalesced across lanes) ----
        int d = tid & 63;
        int kg = tid >> 6;            // uniform per wave
#pragma unroll
        for (int ppp = 0; ppp < 2; ++ppp) {
          int key0 = ppp * 32 + kg * 8;
          unsigned short tmp[8];
#pragma unroll
          for (int j = 0; j < 8; ++j)
            tmp[j] = QKV[(size_t)(b * SEQ + kt * 64 + key0 + j) * 1536 + 1280 + kvh * 64 + d];
          *(short8*)(sVt + d * 72 + key0) = *(const short8*)tmp;
        }
      }
      __syncthreads();

      // ---- S = Q K^T (16 q rows x 64 keys per wave) ----
      f32x4 accS[4] = {};
#pragma unroll
      for (int s = 0; s < 2; ++s) {
#pragma unroll
        for (int n = 0; n < 4; ++n) {
          int rowk = n * 16 + cl;
          short8 kf = *(const short8*)(sK + rowk * 64 + ((s * 32 + q * 8) ^ ((cl & 7) * 8)));
          accS[n] = __builtin_amdgcn_mfma_f32_16x16x32_bf16(qf[s], kf, accS[n], 0, 0, 0);
        }
      }

      // ---- scale (log2) + block-causal mask ----
      float sv[4][4];
      const bool diag = (kt == qt);
      const int qblk = w * 2 + (q >> 1);    // (q*4+r)>>3 == q>>1 for r<4
#pragma unroll
      for (int n = 0; n < 4; ++n) {
        const bool msk = diag && (n * 2 + (cl >> 3)) > qblk;
#pragma unroll
        for (int r = 0; r < 4; ++r)
          sv[n][r] = msk ? -1e30f : accS[n][r] * SCL;
      }

      // ---- online softmax (base-2; row stats across 16 lanes of quad) ----
      float alpha[4];
#pragma unroll
      for (int r = 0; r < 4; ++r) {
        float vmax = fmaxf(fmaxf(sv[0][r], sv[1][r]), fmaxf(sv[2][r], sv[3][r]));
        vmax = fmaxf(vmax, __shfl_xor(vmax, 1));
        vmax = fmaxf(vmax, __shfl_xor(vmax, 2));
        vmax = fmaxf(vmax, __shfl_xor(vmax, 4));
        vmax = fmaxf(vmax, __shfl_xor(vmax, 8));
        float mnew = fmaxf(m_r[r], vmax);
        alpha[r] = exp2f(m_r[r] - mnew);
        float rs = 0.f;
#pragma unroll
        for (int n = 0; n < 4; ++n) {
          float pp = exp2f(sv[n][r] - mnew);
          sv[n][r] = pp;
          rs += pp;
        }
        rs += __shfl_xor(rs, 1);
        rs += __shfl_xor(rs, 2);
        rs += __shfl_xor(rs, 4);
        rs += __shfl_xor(rs, 8);
        l_r[r] = l_r[r] * alpha[r] + rs;
        m_r[r] = mnew;
      }

      // ---- P -> LDS (per-wave region, no block sync needed) ----
#pragma unroll
      for (int n = 0; n < 4; ++n)
#pragma unroll
        for (int r = 0; r < 4; ++r)
          sP[w][(q * 4 + r) * 72 + n * 16 + cl] = f2bf(sv[n][r]);

      // ---- rescale O ----
#pragma unroll
      for (int dn = 0; dn < 4; ++dn) {
        accO[dn][0] *= alpha[0];
        accO[dn][1] *= alpha[1];
        accO[dn][2] *= alpha[2];
        accO[dn][3] *= alpha[3];
      }

      // ---- O += P V ----
      short8 pf[2];
      pf[0] = *(const short8*)(&sP[w][cl * 72 + q * 8]);
      pf[1] = *(const short8*)(&sP[w][cl * 72 + 32 + q * 8]);
#pragma unroll
      for (int dn = 0; dn < 4; ++dn) {
#pragma unroll
        for (int s = 0; s < 2; ++s) {
          short8 vf = *(const short8*)(sVt + (dn * 16 + cl) * 72 + s * 32 + q * 8);
          accO[dn] = __builtin_amdgcn_mfma_f32_16x16x32_bf16(pf[s], vf, accO[dn], 0, 0, 0);
        }
      }
    }

    // ---- epilogue: O / l -> bf16 ----
    float invl[4];
#pragma unroll
    for (int r = 0; r < 4; ++r) invl[r] = 1.0f / l_r[r];
#pragma unroll
    for (int dn = 0; dn < 4; ++dn)
#pragma unroll
      for (int r = 0; r < 4; ++r) {
        int row = b * SEQ + qt * 64 + w * 16 + q * 4 + r;
        O[(size_t)row * DIM + h * 64 + dn * 16 + cl] = f2bf(accO[dn][r] * invl[r]);
      }
    __syncthreads();  // protect LDS before next phase's staging
  }
}

// ---------------- swiglu: g = silu(u1)*u3 (bf16 in/out) ----------------
__global__ __launch_bounds__(256) void swiglu(const unsigned short* __restrict__ U,
                                              unsigned short* __restrict__ G)
{
  int gid = blockIdx.x * 256 + threadIdx.x;  // 4096*128 threads
  int row = gid >> 7;
  int col = (gid & 127) * 8;
  short8 u1 = *(const short8*)(U + (size_t)row * 2048 + col);
  short8 u3 = *(const short8*)(U + (size_t)row * 2048 + 1024 + col);
  short8 g;
#pragma unroll
  for (int j = 0; j < 8; ++j) {
    float f1 = bf2f((unsigned short)u1[j]);
    float f3 = bf2f((unsigned short)u3[j]);
    float s = f1 / (1.0f + expf(-f1)) * f3;
    g[j] = (short)f2bf(s);
  }
  *(short8*)(G + (size_t)row * 1024 + col) = g;
}

extern "C" void kernel_launch(void* const* d_in, const int* in_sizes, int n_in,
                              void* d_out, int out_size, void* d_ws, size_t ws_size,
                              hipStream_t stream)
{
  const float* x   = (const float*)d_in[0];
  const float* vec = (const float*)d_in[1];
  const float* wq  = (const float*)d_in[2];
  const float* wk  = (const float*)d_in[3];
  const float* wv  = (const float*)d_in[4];
  const float* wo  = (const float*)d_in[5];
  const float* w1  = (const float*)d_in[6];
  const float* w2  = (const float*)d_in[7];
  const float* w3  = (const float*)d_in[8];
  const float* maw = (const float*)d_in[9];
  const float* mab = (const float*)d_in[10];
  const float* mfw = (const float*)d_in[11];
  const float* mfb = (const float*)d_in[12];
  const float* n1w = (const float*)d_in[13];
  const float* n2w = (const float*)d_in[14];
  const float* fc  = (const float*)d_in[15];
  const float* fs  = (const float*)d_in[16];

  char* p = (char*)d_ws;
  auto takeU = [&](size_t elems) { unsigned short* r = (unsigned short*)p; p += elems * 2; return r; };
  auto takeF = [&](size_t elems) { float* r = (float*)p; p += elems * 4; return r; };

  unsigned short* WQKV = takeU((size_t)1536 * 1024);
  unsigned short* WOb  = takeU((size_t)1024 * 1024);
  unsigned short* W13  = takeU((size_t)2048 * 1024);
  unsigned short* W2b  = takeU((size_t)1024 * 1024);
  unsigned short* WM   = takeU((size_t)6144 * 1024);   // [mod_attn_w | mod_ffn_w]
  unsigned short* SVEC = takeU((size_t)512 * 1024);
  float* MOD  = takeF((size_t)512 * 6144);             // [sh_a|sc_a|gt_a|sh_f|sc_f|gt_f]
  float* H    = takeF((size_t)4096 * 1024);
  unsigned short* XNb  = takeU((size_t)4096 * 1024);
  unsigned short* QKVb = takeU((size_t)4096 * 1536);
  unsigned short* AOb  = takeU((size_t)4096 * 1024);
  unsigned short* HNb  = takeU((size_t)4096 * 1024);
  // aliases over dead buffers (launch order is strictly sequential on stream):
  unsigned short* U13 = XNb;   // 4096*2048 bf16 fits in XNb+QKVb (dead after attn)
  unsigned short* Gb  = AOb;   // dead after WO gemm

  dim3 blk(256);

  // 1) weight casts f32->bf16 (WQKV packs wq|wk|wv; W13 packs w1|w3; WM packs maw|mfw)
  CastArgs ca;
  ca.src[0] = wq;  ca.dst[0] = WQKV;                    ca.n[0] = 1024 * 1024;
  ca.src[1] = wk;  ca.dst[1] = WQKV + 1024 * 1024;      ca.n[1] = 256 * 1024;
  ca.src[2] = wv;  ca.dst[2] = WQKV + 1280 * 1024;      ca.n[2] = 256 * 1024;
  ca.src[3] = wo;  ca.dst[3] = WOb;                     ca.n[3] = 1024 * 1024;
  ca.src[4] = w1;  ca.dst[4] = W13;                     ca.n[4] = 1024 * 1024;
  ca.src[5] = w3;  ca.dst[5] = W13 + 1024 * 1024;       ca.n[5] = 1024 * 1024;
  ca.src[6] = w2;  ca.dst[6] = W2b;                     ca.n[6] = 1024 * 1024;
  ca.src[7] = maw; ca.dst[7] = WM;                      ca.n[7] = 3072 * 1024;
  ca.src[8] = mfw; ca.dst[8] = WM + (size_t)3072 * 1024; ca.n[8] = 3072 * 1024;
  cast_weights<<<dim3(3072, 9), blk, 0, stream>>>(ca);

  // 2) silu(vec) -> bf16
  silu_cast<<<512, blk, 0, stream>>>(vec, SVEC, 512 * 1024);

  // 3) merged modulation GEMM -> f32 [512, 6144]
  mfma_gemm<1><<<dim3(48, 4), blk, 0, stream>>>(SVEC, WM, 512, 6144, 1024,
      MOD, nullptr, mab, mfb, nullptr, nullptr);

  // 4) xn = rmsnorm(x)*(1+sc_a)+sh_a -> bf16
  rms_mod<<<4096, blk, 0, stream>>>(x, n1w, MOD, 0, XNb);

  // 5) fused QKV GEMM + RoPE -> packed bf16 [4096,1536]
  mfma_gemm<0><<<dim3(12, 32), blk, 0, stream>>>(XNb, WQKV, 4096, 1536, 1024,
      nullptr, QKVb, nullptr, nullptr, fc, fs);

  // 6) balanced MFMA flash attention -> AO bf16
  attn_mfma<<<512, blk, 0, stream>>>(QKVb, AOb);

  // 7) h = x + gate_a * (AO @ wo^T) -> f32
  mfma_gemm<2><<<dim3(8, 32), blk, 0, stream>>>(AOb, WOb, 4096, 1024, 1024,
      H, nullptr, x, MOD + 2048, nullptr, nullptr);

  // 8) hn = rmsnorm(h)*(1+sc_f)+sh_f -> bf16
  rms_mod<<<4096, blk, 0, stream>>>(H, n2w, MOD, 3072, HNb);

  // 9) u13 = hn @ [w1|w3]^T -> bf16 [4096,2048]
  mfma_gemm<3><<<dim3(16, 32), blk, 0, stream>>>(HNb, W13, 4096, 2048, 1024,
      nullptr, U13, nullptr, nullptr, nullptr, nullptr);

  // 10) g = silu(u1)*u3 -> bf16
  swiglu<<<2048, blk, 0, stream>>>(U13, Gb);

  // 11) out = h + gate_f * (g @ w2^T) -> f32
  mfma_gemm<4><<<dim3(8, 32), blk, 0, stream>>>(Gb, W2b, 4096, 1024, 1024,
      (float*)d_out, nullptr, H, MOD + 5120, nullptr, nullptr);
}

// Round 6
// 338.849 us; speedup vs baseline: 5.0100x; 1.0820x over previous
//
#include <hip/hip_runtime.h>
#include <math.h>

// B=4, S=1024, D=1024, H=16, KVH=4, HD=64, HIDDEN=1024, BLK=8
#define SEQ 1024
#define DIM 1024

using short8 = __attribute__((ext_vector_type(8))) short;
using f32x4  = __attribute__((ext_vector_type(4))) float;

__device__ __forceinline__ unsigned short f2bf(float f) {
  unsigned int u = __float_as_uint(f);
  u = (u + 0x7FFFu + ((u >> 16) & 1u)) >> 16;
  return (unsigned short)u;
}
__device__ __forceinline__ float bf2f(unsigned short h) {
  return __uint_as_float(((unsigned int)h) << 16);
}
__device__ __forceinline__ void load16_lds(const unsigned short* g, unsigned short* l) {
  __builtin_amdgcn_global_load_lds((const __attribute__((address_space(1))) void*)g,
                                   (__attribute__((address_space(3))) void*)l, 16, 0, 0);
}

// ---------------- weight cast (f32 -> bf16), 9 regions ----------------
struct CastArgs {
  const float* src[9];
  unsigned short* dst[9];
  int n[9];
};
__global__ __launch_bounds__(256) void cast_weights(CastArgs a) {
  int r = blockIdx.y;
  int i4 = (blockIdx.x * 256 + threadIdx.x) * 4;
  if (i4 >= a.n[r]) return;
  const float4 v = *(const float4*)(a.src[r] + i4);
  ushort4 o;
  o.x = f2bf(v.x); o.y = f2bf(v.y); o.z = f2bf(v.z); o.w = f2bf(v.w);
  *(ushort4*)(a.dst[r] + i4) = o;
}

// ---------------- silu(vec) -> bf16 ----------------
__global__ __launch_bounds__(256) void silu_cast(const float* __restrict__ v,
                                                 unsigned short* __restrict__ o, int n) {
  int i4 = (blockIdx.x * 256 + threadIdx.x) * 4;
  if (i4 >= n) return;
  float4 x = *(const float4*)(v + i4);
  ushort4 r;
  r.x = f2bf(x.x / (1.0f + expf(-x.x)));
  r.y = f2bf(x.y / (1.0f + expf(-x.y)));
  r.z = f2bf(x.z / (1.0f + expf(-x.z)));
  r.w = f2bf(x.w / (1.0f + expf(-x.w)));
  *(ushort4*)(o + i4) = r;
}

// ---------------- MFMA GEMM: C[M,N] = A[M,K] @ W[N,K]^T (A,W bf16) ----------------
// 128x64 block tile (grid = (N/64, M/128)), 4 waves 2x2, wave tile 64x32, BK=32.
// Doubled block count vs 128x128 so N=1024 GEMMs get >=2 blocks/CU (R5: 256 blocks
// = 1 block/CU fully exposed the vmcnt(0) barrier drain).
// EPI: 0 QKV(+RoPE)->bf16[N=1536]  1 +dual-bias->f32 (mod, N=6144)
//      2 x+gate*acc->f32 (h)       3 plain->bf16     4 h+gate*acc->f32 (final)
template<int EPI>
__global__ __launch_bounds__(256) void mfma_gemm(
    const unsigned short* __restrict__ A, const unsigned short* __restrict__ W,
    int M, int N, int K,
    float* __restrict__ outF, unsigned short* __restrict__ outBF,
    const float* __restrict__ aux1,   // bias1 / xres / hres
    const float* __restrict__ aux2,   // bias2 / mod-gate base (stride 6144)
    const float* __restrict__ fc, const float* __restrict__ fs)
{
  __shared__ unsigned short sA[128 * 32];   // [row][k] row-major
  __shared__ unsigned short sB[64 * 32];
  const int tid = threadIdx.x;
  const int lane = tid & 63;
  const int wv = tid >> 6;          // 0..3
  const int wr = wv >> 1;           // row half (64 rows)
  const int wc = wv & 1;            // col half (32 cols)
  const int rowBlk = blockIdx.y * 128;
  const int colBlk = blockIdx.x * 64;
  const int l4 = lane >> 2;         // row within 16-row chunk
  const int lk = (lane & 3) * 8;    // k element offset (8 bf16 = 16B)
  const int q = lane >> 4;          // quad
  const int cl = lane & 15;

  f32x4 acc[4][2] = {};

  for (int k0 = 0; k0 < K; k0 += 32) {
#pragma unroll
    for (int c = 0; c < 2; ++c) {
      int ch = wv * 2 + c;          // A chunk 0..7 (16 rows each)
      load16_lds(A + (size_t)(rowBlk + ch * 16 + l4) * K + k0 + lk, &sA[ch * 512 + lane * 8]);
    }
    load16_lds(W + (size_t)(colBlk + wv * 16 + l4) * K + k0 + lk, &sB[wv * 512 + lane * 8]);
    __syncthreads();
    short8 af[4], bfr[2];
#pragma unroll
    for (int t = 0; t < 4; ++t)
      af[t]  = *(const short8*)&sA[(wr * 64 + t * 16 + cl) * 32 + q * 8];
#pragma unroll
    for (int t = 0; t < 2; ++t)
      bfr[t] = *(const short8*)&sB[(wc * 32 + t * 16 + cl) * 32 + q * 8];
#pragma unroll
    for (int tm = 0; tm < 4; ++tm)
#pragma unroll
      for (int tn = 0; tn < 2; ++tn)
        acc[tm][tn] = __builtin_amdgcn_mfma_f32_16x16x32_bf16(af[tm], bfr[tn], acc[tm][tn], 0, 0, 0);
    __syncthreads();
  }

  // epilogue: C/D layout col=lane&15, row=quad*4+reg (verified m89/m91)
#pragma unroll
  for (int tm = 0; tm < 4; ++tm) {
#pragma unroll
    for (int tn = 0; tn < 2; ++tn) {
      const int col = colBlk + wc * 32 + tn * 16 + cl;
#pragma unroll
      for (int r = 0; r < 4; ++r) {
        const int row = rowBlk + wr * 64 + tm * 16 + q * 4 + r;
        float v = acc[tm][tn][r];
        if constexpr (EPI == 0) {
          float other = __shfl_xor(v, 1);   // partner col (col^1), same row
          if (col < 1280) {                 // Q (0..1023) and K (1024..1279) get RoPE
            int s = row & (SEQ - 1);
            int t = (col & 63) >> 1;
            float cv = fc[s * 32 + t], sv = fs[s * 32 + t];
            v = ((col & 1) == 0) ? (v * cv - other * sv) : (other * sv + v * cv);
          }
          outBF[(size_t)row * N + col] = f2bf(v);
        } else if constexpr (EPI == 1) {
          float bb = (col < 3072) ? aux1[col] : aux2[col - 3072];
          outF[(size_t)row * N + col] = v + bb;
        } else if constexpr (EPI == 2 || EPI == 4) {
          int vr = (row >> 10) * 128 + ((row & (SEQ - 1)) >> 3);
          outF[(size_t)row * N + col] =
              aux1[(size_t)row * N + col] + aux2[(size_t)vr * 6144 + col] * v;
        } else if constexpr (EPI == 3) {
          outBF[(size_t)row * N + col] = f2bf(v);
        }
      }
    }
  }
}

// ---------------- rmsnorm + modulation -> bf16 ----------------
// mod row stride 6144; off = 0 (attn: shift@0, scale@1024) or 3072 (ffn)
__global__ __launch_bounds__(256) void rms_mod(
    const float* __restrict__ X, const float* __restrict__ w,
    const float* __restrict__ mod, int off, unsigned short* __restrict__ out)
{
  const int r = blockIdx.x;
  const int b = r >> 10, s = r & (SEQ - 1);
  const int vr = b * 128 + (s >> 3);
  const size_t base = (size_t)r * DIM;
  float v[4];
  float ss = 0.f;
#pragma unroll
  for (int p = 0; p < 4; ++p) {
    int c = threadIdx.x + p * 256;
    v[p] = X[base + c];
    ss += v[p] * v[p];
  }
#pragma unroll
  for (int o = 1; o < 64; o <<= 1) ss += __shfl_xor(ss, o);
  __shared__ float red[4];
  int lane = threadIdx.x & 63, wvv = threadIdx.x >> 6;
  if (lane == 0) red[wvv] = ss;
  __syncthreads();
  float total = red[0] + red[1] + red[2] + red[3];
  float rn = rsqrtf(total * (1.0f / 1024.0f) + 1e-6f);
  const float* mrow = mod + (size_t)vr * 6144 + off;
#pragma unroll
  for (int p = 0; p < 4; ++p) {
    int c = threadIdx.x + p * 256;
    out[base + c] = f2bf(v[p] * rn * w[c] * (1.0f + mrow[1024 + c]) + mrow[c]);
  }
}

// ---------------- MFMA flash block-causal attention (balanced) ----------------
// QKV packed [4096][1536] bf16: q 0..1023, k 1024..1279, v 1280..1535
// Grid 512: (b, h, qpair). Each block processes q-tiles {pr, 15-pr} -> 17 KV iters.
__global__ __launch_bounds__(256) void attn_mfma(
    const unsigned short* __restrict__ QKV, unsigned short* __restrict__ O)
{
  const int bid = blockIdx.x;
  const int pr = bid & 7;
  const int h = (bid >> 3) & 15;
  const int b = bid >> 7;
  const int kvh = h >> 2;
  __shared__ unsigned short sK[64 * 64];      // [key][d], d XOR-swizzled by (key&7)*8
  __shared__ unsigned short sVt[64 * 72];     // [d][key], +8 pad
  __shared__ unsigned short sP[4][16 * 72];   // per-wave P strip [qrow][key], +8 pad
  const int tid = threadIdx.x;
  const int lane = tid & 63;
  const int w = tid >> 6;       // wave = q-row strip
  const int q = lane >> 4;      // quad
  const int cl = lane & 15;
  const float SCL = 0.125f * 1.44269504f;  // softmax in log2 domain

  for (int ph = 0; ph < 2; ++ph) {
    const int qt = ph ? (15 - pr) : pr;

    short8 qf[2];
    {
      const size_t qrow = (size_t)(b * SEQ + qt * 64 + w * 16 + cl) * 1536 + h * 64;
#pragma unroll
      for (int s = 0; s < 2; ++s)
        qf[s] = *(const short8*)(QKV + qrow + s * 32 + q * 8);
    }

    f32x4 accO[4] = {};
    float m_r[4], l_r[4];
#pragma unroll
    for (int r = 0; r < 4; ++r) { m_r[r] = -1e30f; l_r[r] = 0.f; }

    for (int kt = 0; kt <= qt; ++kt) {
      __syncthreads();
      {
        int rr = tid >> 3;            // 0..31
        int d0 = (tid & 7) * 8;
#pragma unroll
        for (int ppp = 0; ppp < 2; ++ppp) {
          int key = ppp * 32 + rr;
          const unsigned short* g =
              QKV + (size_t)(b * SEQ + kt * 64 + key) * 1536 + 1024 + kvh * 64 + d0;
          short8 kv = *(const short8*)g;
          *(short8*)(sK + key * 64 + (d0 ^ ((key & 7) * 8))) = kv;
        }
        int d = tid & 63;
        int kg = tid >> 6;
#pragma unroll
        for (int ppp = 0; ppp < 2; ++ppp) {
          int key0 = ppp * 32 + kg * 8;
          unsigned short tmp[8];
#pragma unroll
          for (int j = 0; j < 8; ++j)
            tmp[j] = QKV[(size_t)(b * SEQ + kt * 64 + key0 + j) * 1536 + 1280 + kvh * 64 + d];
          *(short8*)(sVt + d * 72 + key0) = *(const short8*)tmp;
        }
      }
      __syncthreads();

      f32x4 accS[4] = {};
#pragma unroll
      for (int s = 0; s < 2; ++s) {
#pragma unroll
        for (int n = 0; n < 4; ++n) {
          int rowk = n * 16 + cl;
          short8 kf = *(const short8*)(sK + rowk * 64 + ((s * 32 + q * 8) ^ ((cl & 7) * 8)));
          accS[n] = __builtin_amdgcn_mfma_f32_16x16x32_bf16(qf[s], kf, accS[n], 0, 0, 0);
        }
      }

      float sv[4][4];
      const bool diag = (kt == qt);
      const int qblk = w * 2 + (q >> 1);
#pragma unroll
      for (int n = 0; n < 4; ++n) {
        const bool msk = diag && (n * 2 + (cl >> 3)) > qblk;
#pragma unroll
        for (int r = 0; r < 4; ++r)
          sv[n][r] = msk ? -1e30f : accS[n][r] * SCL;
      }

      float alpha[4];
#pragma unroll
      for (int r = 0; r < 4; ++r) {
        float vmax = fmaxf(fmaxf(sv[0][r], sv[1][r]), fmaxf(sv[2][r], sv[3][r]));
        vmax = fmaxf(vmax, __shfl_xor(vmax, 1));
        vmax = fmaxf(vmax, __shfl_xor(vmax, 2));
        vmax = fmaxf(vmax, __shfl_xor(vmax, 4));
        vmax = fmaxf(vmax, __shfl_xor(vmax, 8));
        float mnew = fmaxf(m_r[r], vmax);
        alpha[r] = exp2f(m_r[r] - mnew);
        float rs = 0.f;
#pragma unroll
        for (int n = 0; n < 4; ++n) {
          float pp = exp2f(sv[n][r] - mnew);
          sv[n][r] = pp;
          rs += pp;
        }
        rs += __shfl_xor(rs, 1);
        rs += __shfl_xor(rs, 2);
        rs += __shfl_xor(rs, 4);
        rs += __shfl_xor(rs, 8);
        l_r[r] = l_r[r] * alpha[r] + rs;
        m_r[r] = mnew;
      }

#pragma unroll
      for (int n = 0; n < 4; ++n)
#pragma unroll
        for (int r = 0; r < 4; ++r)
          sP[w][(q * 4 + r) * 72 + n * 16 + cl] = f2bf(sv[n][r]);

#pragma unroll
      for (int dn = 0; dn < 4; ++dn) {
        accO[dn][0] *= alpha[0];
        accO[dn][1] *= alpha[1];
        accO[dn][2] *= alpha[2];
        accO[dn][3] *= alpha[3];
      }

      short8 pf[2];
      pf[0] = *(const short8*)(&sP[w][cl * 72 + q * 8]);
      pf[1] = *(const short8*)(&sP[w][cl * 72 + 32 + q * 8]);
#pragma unroll
      for (int dn = 0; dn < 4; ++dn) {
#pragma unroll
        for (int s = 0; s < 2; ++s) {
          short8 vf = *(const short8*)(sVt + (dn * 16 + cl) * 72 + s * 32 + q * 8);
          accO[dn] = __builtin_amdgcn_mfma_f32_16x16x32_bf16(pf[s], vf, accO[dn], 0, 0, 0);
        }
      }
    }

    float invl[4];
#pragma unroll
    for (int r = 0; r < 4; ++r) invl[r] = 1.0f / l_r[r];
#pragma unroll
    for (int dn = 0; dn < 4; ++dn)
#pragma unroll
      for (int r = 0; r < 4; ++r) {
        int row = b * SEQ + qt * 64 + w * 16 + q * 4 + r;
        O[(size_t)row * DIM + h * 64 + dn * 16 + cl] = f2bf(accO[dn][r] * invl[r]);
      }
    __syncthreads();
  }
}

// ---------------- swiglu: g = silu(u1)*u3 (bf16 in/out) ----------------
__global__ __launch_bounds__(256) void swiglu(const unsigned short* __restrict__ U,
                                              unsigned short* __restrict__ G)
{
  int gid = blockIdx.x * 256 + threadIdx.x;
  int row = gid >> 7;
  int col = (gid & 127) * 8;
  short8 u1 = *(const short8*)(U + (size_t)row * 2048 + col);
  short8 u3 = *(const short8*)(U + (size_t)row * 2048 + 1024 + col);
  short8 g;
#pragma unroll
  for (int j = 0; j < 8; ++j) {
    float f1 = bf2f((unsigned short)u1[j]);
    float f3 = bf2f((unsigned short)u3[j]);
    float s = f1 / (1.0f + expf(-f1)) * f3;
    g[j] = (short)f2bf(s);
  }
  *(short8*)(G + (size_t)row * 1024 + col) = g;
}

extern "C" void kernel_launch(void* const* d_in, const int* in_sizes, int n_in,
                              void* d_out, int out_size, void* d_ws, size_t ws_size,
                              hipStream_t stream)
{
  const float* x   = (const float*)d_in[0];
  const float* vec = (const float*)d_in[1];
  const float* wq  = (const float*)d_in[2];
  const float* wk  = (const float*)d_in[3];
  const float* wv  = (const float*)d_in[4];
  const float* wo  = (const float*)d_in[5];
  const float* w1  = (const float*)d_in[6];
  const float* w2  = (const float*)d_in[7];
  const float* w3  = (const float*)d_in[8];
  const float* maw = (const float*)d_in[9];
  const float* mab = (const float*)d_in[10];
  const float* mfw = (const float*)d_in[11];
  const float* mfb = (const float*)d_in[12];
  const float* n1w = (const float*)d_in[13];
  const float* n2w = (const float*)d_in[14];
  const float* fc  = (const float*)d_in[15];
  const float* fs  = (const float*)d_in[16];

  char* p = (char*)d_ws;
  auto takeU = [&](size_t elems) { unsigned short* r = (unsigned short*)p; p += elems * 2; return r; };
  auto takeF = [&](size_t elems) { float* r = (float*)p; p += elems * 4; return r; };

  unsigned short* WQKV = takeU((size_t)1536 * 1024);
  unsigned short* WOb  = takeU((size_t)1024 * 1024);
  unsigned short* W13  = takeU((size_t)2048 * 1024);
  unsigned short* W2b  = takeU((size_t)1024 * 1024);
  unsigned short* WM   = takeU((size_t)6144 * 1024);   // [mod_attn_w | mod_ffn_w]
  unsigned short* SVEC = takeU((size_t)512 * 1024);
  float* MOD  = takeF((size_t)512 * 6144);             // [sh_a|sc_a|gt_a|sh_f|sc_f|gt_f]
  float* H    = takeF((size_t)4096 * 1024);
  unsigned short* XNb  = takeU((size_t)4096 * 1024);
  unsigned short* QKVb = takeU((size_t)4096 * 1536);
  unsigned short* AOb  = takeU((size_t)4096 * 1024);
  unsigned short* HNb  = takeU((size_t)4096 * 1024);
  unsigned short* U13 = XNb;   // aliases over dead buffers (sequential stream)
  unsigned short* Gb  = AOb;

  dim3 blk(256);

  CastArgs ca;
  ca.src[0] = wq;  ca.dst[0] = WQKV;                    ca.n[0] = 1024 * 1024;
  ca.src[1] = wk;  ca.dst[1] = WQKV + 1024 * 1024;      ca.n[1] = 256 * 1024;
  ca.src[2] = wv;  ca.dst[2] = WQKV + 1280 * 1024;      ca.n[2] = 256 * 1024;
  ca.src[3] = wo;  ca.dst[3] = WOb;                     ca.n[3] = 1024 * 1024;
  ca.src[4] = w1;  ca.dst[4] = W13;                     ca.n[4] = 1024 * 1024;
  ca.src[5] = w3;  ca.dst[5] = W13 + 1024 * 1024;       ca.n[5] = 1024 * 1024;
  ca.src[6] = w2;  ca.dst[6] = W2b;                     ca.n[6] = 1024 * 1024;
  ca.src[7] = maw; ca.dst[7] = WM;                      ca.n[7] = 3072 * 1024;
  ca.src[8] = mfw; ca.dst[8] = WM + (size_t)3072 * 1024; ca.n[8] = 3072 * 1024;
  cast_weights<<<dim3(3072, 9), blk, 0, stream>>>(ca);

  silu_cast<<<512, blk, 0, stream>>>(vec, SVEC, 512 * 1024);

  // merged modulation GEMM -> f32 [512, 6144]  (grid 384 blocks)
  mfma_gemm<1><<<dim3(96, 4), blk, 0, stream>>>(SVEC, WM, 512, 6144, 1024,
      MOD, nullptr, mab, mfb, nullptr, nullptr);

  rms_mod<<<4096, blk, 0, stream>>>(x, n1w, MOD, 0, XNb);

  // fused QKV GEMM + RoPE -> packed bf16 [4096,1536]  (grid 768)
  mfma_gemm<0><<<dim3(24, 32), blk, 0, stream>>>(XNb, WQKV, 4096, 1536, 1024,
      nullptr, QKVb, nullptr, nullptr, fc, fs);

  attn_mfma<<<512, blk, 0, stream>>>(QKVb, AOb);

  // h = x + gate_a * (AO @ wo^T) -> f32  (grid 512)
  mfma_gemm<2><<<dim3(16, 32), blk, 0, stream>>>(AOb, WOb, 4096, 1024, 1024,
      H, nullptr, x, MOD + 2048, nullptr, nullptr);

  rms_mod<<<4096, blk, 0, stream>>>(H, n2w, MOD, 3072, HNb);

  // u13 = hn @ [w1|w3]^T -> bf16 [4096,2048]  (grid 1024)
  mfma_gemm<3><<<dim3(32, 32), blk, 0, stream>>>(HNb, W13, 4096, 2048, 1024,
      nullptr, U13, nullptr, nullptr, nullptr, nullptr);

  swiglu<<<2048, blk, 0, stream>>>(U13, Gb);

  // out = h + gate_f * (g @ w2^T) -> f32  (grid 512)
  mfma_gemm<4><<<dim3(16, 32), blk, 0, stream>>>(Gb, W2b, 4096, 1024, 1024,
      (float*)d_out, nullptr, H, MOD + 5120, nullptr, nullptr);
}

// Round 7
// 326.686 us; speedup vs baseline: 5.1965x; 1.0372x over previous
//
#include <hip/hip_runtime.h>
#include <math.h>

// B=4, S=1024, D=1024, H=16, KVH=4, HD=64, HIDDEN=1024, BLK=8
#define SEQ 1024
#define DIM 1024

using short8 = __attribute__((ext_vector_type(8))) short;
using f32x4  = __attribute__((ext_vector_type(4))) float;

__device__ __forceinline__ unsigned short f2bf(float f) {
  unsigned int u = __float_as_uint(f);
  u = (u + 0x7FFFu + ((u >> 16) & 1u)) >> 16;
  return (unsigned short)u;
}
__device__ __forceinline__ float bf2f(unsigned short h) {
  return __uint_as_float(((unsigned int)h) << 16);
}
__device__ __forceinline__ void load16_lds(const unsigned short* g, unsigned short* l) {
  __builtin_amdgcn_global_load_lds((const __attribute__((address_space(1))) void*)g,
                                   (__attribute__((address_space(3))) void*)l, 16, 0, 0);
}

// ---------------- weight cast (f32 -> bf16), 9 regions ----------------
// ilv: 0 = flat copy; 1/2 = interleave rows (dst row = src_row*2 + (ilv-1)),
// used to pack w1|w3 row-interleaved so FFN13's epilogue can fuse swiglu.
struct CastArgs {
  const float* src[9];
  unsigned short* dst[9];
  int n[9];
  int ilv[9];
};
__global__ __launch_bounds__(256) void cast_weights(CastArgs a) {
  int r = blockIdx.y;
  int i4 = (blockIdx.x * 256 + threadIdx.x) * 4;
  if (i4 >= a.n[r]) return;
  const float4 v = *(const float4*)(a.src[r] + i4);
  ushort4 o;
  o.x = f2bf(v.x); o.y = f2bf(v.y); o.z = f2bf(v.z); o.w = f2bf(v.w);
  size_t di = i4;
  if (a.ilv[r]) di = (size_t)((i4 >> 10) * 2 + (a.ilv[r] - 1)) * 1024 + (i4 & 1023);
  *(ushort4*)(a.dst[r] + di) = o;
}

// ---------------- silu(vec) -> bf16 ----------------
__global__ __launch_bounds__(256) void silu_cast(const float* __restrict__ v,
                                                 unsigned short* __restrict__ o, int n) {
  int i4 = (blockIdx.x * 256 + threadIdx.x) * 4;
  if (i4 >= n) return;
  float4 x = *(const float4*)(v + i4);
  ushort4 r;
  r.x = f2bf(x.x / (1.0f + expf(-x.x)));
  r.y = f2bf(x.y / (1.0f + expf(-x.y)));
  r.z = f2bf(x.z / (1.0f + expf(-x.z)));
  r.w = f2bf(x.w / (1.0f + expf(-x.w)));
  *(ushort4*)(o + i4) = r;
}

// ---------------- MFMA GEMM: C[M,N] = A[M,K] @ W[N,K]^T (A,W bf16) ----------------
// 128x64 block tile, 4 waves 2x2 (wave tile 64x32), BK=64, 2-stage LDS dbuf:
// next tile's global_load_lds issues right after the barrier so its latency is
// covered by the current tile's ds_read+MFMA (16 barriers/dispatch vs 32 in R6).
// K-chunk index XOR-swizzled by row&7 (BK=64 row stride = 32 dwords would put all
// 16 quad-lanes on one bank group otherwise); swizzle applied on the global source
// since global_load_lds forces LDS dest = base + lane*16.
// EPI: 0 QKV(+RoPE)->bf16[N=1536]  1 +dual-bias->f32 (mod, N=6144)
//      2 x+gate*acc->f32 (h)       3 fused swiglu (interleaved u1/u3)->bf16 g[.,1024]
//      4 h+gate*acc->f32 (final)
template<int EPI>
__global__ __launch_bounds__(256) void mfma_gemm(
    const unsigned short* __restrict__ A, const unsigned short* __restrict__ W,
    int M, int N, int K,
    float* __restrict__ outF, unsigned short* __restrict__ outBF,
    const float* __restrict__ aux1,   // bias1 / xres / hres
    const float* __restrict__ aux2,   // bias2 / mod-gate base (stride 6144)
    const float* __restrict__ fc, const float* __restrict__ fs)
{
  __shared__ unsigned short sA[2][128 * 64];  // 16 KB each
  __shared__ unsigned short sB[2][64 * 64];   //  8 KB each  (48 KB total)
  const int tid = threadIdx.x;
  const int lane = tid & 63;
  const int wv = tid >> 6;
  const int wr = wv >> 1;           // row half (64 rows)
  const int wc = wv & 1;            // col half (32 cols)
  const int rowBlk = blockIdx.y * 128;
  const int colBlk = blockIdx.x * 64;
  const int q = lane >> 4;          // quad
  const int cl = lane & 15;

  f32x4 acc[4][2] = {};

  auto stage = [&](int bf, int k0) {
#pragma unroll
    for (int j = 0; j < 4; ++j) {
      int slot = j * 256 + tid;
      int row = slot >> 3;
      int cg = (slot & 7) ^ (row & 7);
      load16_lds(A + (size_t)(rowBlk + row) * K + k0 + cg * 8, &sA[bf][slot * 8]);
    }
#pragma unroll
    for (int j = 0; j < 2; ++j) {
      int slot = j * 256 + tid;
      int row = slot >> 3;
      int cg = (slot & 7) ^ (row & 7);
      load16_lds(W + (size_t)(colBlk + row) * K + k0 + cg * 8, &sB[bf][slot * 8]);
    }
  };

  auto compute = [&](int bf) {
    short8 af[4][2], bfr[2][2];
#pragma unroll
    for (int t = 0; t < 4; ++t) {
      int row = wr * 64 + t * 16 + cl;
#pragma unroll
      for (int s = 0; s < 2; ++s)
        af[t][s] = *(const short8*)&sA[bf][row * 64 + (((s * 4 + q) ^ (cl & 7)) * 8)];
    }
#pragma unroll
    for (int t = 0; t < 2; ++t) {
      int row = wc * 32 + t * 16 + cl;
#pragma unroll
      for (int s = 0; s < 2; ++s)
        bfr[t][s] = *(const short8*)&sB[bf][row * 64 + (((s * 4 + q) ^ (cl & 7)) * 8)];
    }
#pragma unroll
    for (int s = 0; s < 2; ++s)
#pragma unroll
      for (int tm = 0; tm < 4; ++tm)
#pragma unroll
        for (int tn = 0; tn < 2; ++tn)
          acc[tm][tn] = __builtin_amdgcn_mfma_f32_16x16x32_bf16(af[tm][s], bfr[tn][s], acc[tm][tn], 0, 0, 0);
  };

  stage(0, 0);
  int cur = 0;
  for (int k0 = 64; k0 < K; k0 += 64) {
    __syncthreads();          // drains cur's loads; prior compute on cur^1 done
    stage(cur ^ 1, k0);       // prefetch flies under compute(cur)
    compute(cur);
    cur ^= 1;
  }
  __syncthreads();
  compute(cur);

  // epilogue: C/D layout col=lane&15, row=quad*4+reg (verified m89/m91)
#pragma unroll
  for (int tm = 0; tm < 4; ++tm) {
#pragma unroll
    for (int tn = 0; tn < 2; ++tn) {
      const int col = colBlk + wc * 32 + tn * 16 + cl;
#pragma unroll
      for (int r = 0; r < 4; ++r) {
        const int row = rowBlk + wr * 64 + tm * 16 + q * 4 + r;
        float v = acc[tm][tn][r];
        if constexpr (EPI == 0) {
          float other = __shfl_xor(v, 1);   // partner col (col^1), same row
          if (col < 1280) {                 // Q and K get RoPE
            int s = row & (SEQ - 1);
            int t = (col & 63) >> 1;
            float cv = fc[s * 32 + t], sv = fs[s * 32 + t];
            v = ((col & 1) == 0) ? (v * cv - other * sv) : (other * sv + v * cv);
          }
          outBF[(size_t)row * N + col] = f2bf(v);
        } else if constexpr (EPI == 1) {
          float bb = (col < 3072) ? aux1[col] : aux2[col - 3072];
          outF[(size_t)row * N + col] = v + bb;
        } else if constexpr (EPI == 2 || EPI == 4) {
          int vr = (row >> 10) * 128 + ((row & (SEQ - 1)) >> 3);
          outF[(size_t)row * N + col] =
              aux1[(size_t)row * N + col] + aux2[(size_t)vr * 6144 + col] * v;
        } else if constexpr (EPI == 3) {
          // interleaved: even col = u1, odd col = u3; g = silu(u1)*u3
          float other = __shfl_xor(v, 1);
          if ((col & 1) == 0) {
            float g = v / (1.0f + expf(-v)) * other;
            outBF[(size_t)row * 1024 + (col >> 1)] = f2bf(g);
          }
        }
      }
    }
  }
}

// ---------------- rmsnorm + modulation -> bf16 ----------------
// mod row stride 6144; off = 0 (attn: shift@0, scale@1024) or 3072 (ffn)
__global__ __launch_bounds__(256) void rms_mod(
    const float* __restrict__ X, const float* __restrict__ w,
    const float* __restrict__ mod, int off, unsigned short* __restrict__ out)
{
  const int r = blockIdx.x;
  const int b = r >> 10, s = r & (SEQ - 1);
  const int vr = b * 128 + (s >> 3);
  const size_t base = (size_t)r * DIM;
  float v[4];
  float ss = 0.f;
#pragma unroll
  for (int p = 0; p < 4; ++p) {
    int c = threadIdx.x + p * 256;
    v[p] = X[base + c];
    ss += v[p] * v[p];
  }
#pragma unroll
  for (int o = 1; o < 64; o <<= 1) ss += __shfl_xor(ss, o);
  __shared__ float red[4];
  int lane = threadIdx.x & 63, wvv = threadIdx.x >> 6;
  if (lane == 0) red[wvv] = ss;
  __syncthreads();
  float total = red[0] + red[1] + red[2] + red[3];
  float rn = rsqrtf(total * (1.0f / 1024.0f) + 1e-6f);
  const float* mrow = mod + (size_t)vr * 6144 + off;
#pragma unroll
  for (int p = 0; p < 4; ++p) {
    int c = threadIdx.x + p * 256;
    out[base + c] = f2bf(v[p] * rn * w[c] * (1.0f + mrow[1024 + c]) + mrow[c]);
  }
}

// ---------------- MFMA flash block-causal attention (balanced) ----------------
// QKV packed [4096][1536] bf16: q 0..1023, k 1024..1279, v 1280..1535
// Grid 512: (b, h, qpair). Each block processes q-tiles {pr, 15-pr} -> 17 KV iters.
__global__ __launch_bounds__(256) void attn_mfma(
    const unsigned short* __restrict__ QKV, unsigned short* __restrict__ O)
{
  const int bid = blockIdx.x;
  const int pr = bid & 7;
  const int h = (bid >> 3) & 15;
  const int b = bid >> 7;
  const int kvh = h >> 2;
  __shared__ unsigned short sK[64 * 64];      // [key][d], d XOR-swizzled by (key&7)*8
  __shared__ unsigned short sVt[64 * 72];     // [d][key], +8 pad
  __shared__ unsigned short sP[4][16 * 72];   // per-wave P strip [qrow][key], +8 pad
  const int tid = threadIdx.x;
  const int lane = tid & 63;
  const int w = tid >> 6;       // wave = q-row strip
  const int q = lane >> 4;      // quad
  const int cl = lane & 15;
  const float SCL = 0.125f * 1.44269504f;  // softmax in log2 domain

  for (int ph = 0; ph < 2; ++ph) {
    const int qt = ph ? (15 - pr) : pr;

    short8 qf[2];
    {
      const size_t qrow = (size_t)(b * SEQ + qt * 64 + w * 16 + cl) * 1536 + h * 64;
#pragma unroll
      for (int s = 0; s < 2; ++s)
        qf[s] = *(const short8*)(QKV + qrow + s * 32 + q * 8);
    }

    f32x4 accO[4] = {};
    float m_r[4], l_r[4];
#pragma unroll
    for (int r = 0; r < 4; ++r) { m_r[r] = -1e30f; l_r[r] = 0.f; }

    for (int kt = 0; kt <= qt; ++kt) {
      __syncthreads();
      {
        int rr = tid >> 3;            // 0..31
        int d0 = (tid & 7) * 8;
#pragma unroll
        for (int ppp = 0; ppp < 2; ++ppp) {
          int key = ppp * 32 + rr;
          const unsigned short* g =
              QKV + (size_t)(b * SEQ + kt * 64 + key) * 1536 + 1024 + kvh * 64 + d0;
          short8 kv = *(const short8*)g;
          *(short8*)(sK + key * 64 + (d0 ^ ((key & 7) * 8))) = kv;
        }
        int d = tid & 63;
        int kg = tid >> 6;
#pragma unroll
        for (int ppp = 0; ppp < 2; ++ppp) {
          int key0 = ppp * 32 + kg * 8;
          unsigned short tmp[8];
#pragma unroll
          for (int j = 0; j < 8; ++j)
            tmp[j] = QKV[(size_t)(b * SEQ + kt * 64 + key0 + j) * 1536 + 1280 + kvh * 64 + d];
          *(short8*)(sVt + d * 72 + key0) = *(const short8*)tmp;
        }
      }
      __syncthreads();

      f32x4 accS[4] = {};
#pragma unroll
      for (int s = 0; s < 2; ++s) {
#pragma unroll
        for (int n = 0; n < 4; ++n) {
          int rowk = n * 16 + cl;
          short8 kf = *(const short8*)(sK + rowk * 64 + ((s * 32 + q * 8) ^ ((cl & 7) * 8)));
          accS[n] = __builtin_amdgcn_mfma_f32_16x16x32_bf16(qf[s], kf, accS[n], 0, 0, 0);
        }
      }

      float sv[4][4];
      const bool diag = (kt == qt);
      const int qblk = w * 2 + (q >> 1);
#pragma unroll
      for (int n = 0; n < 4; ++n) {
        const bool msk = diag && (n * 2 + (cl >> 3)) > qblk;
#pragma unroll
        for (int r = 0; r < 4; ++r)
          sv[n][r] = msk ? -1e30f : accS[n][r] * SCL;
      }

      float alpha[4];
#pragma unroll
      for (int r = 0; r < 4; ++r) {
        float vmax = fmaxf(fmaxf(sv[0][r], sv[1][r]), fmaxf(sv[2][r], sv[3][r]));
        vmax = fmaxf(vmax, __shfl_xor(vmax, 1));
        vmax = fmaxf(vmax, __shfl_xor(vmax, 2));
        vmax = fmaxf(vmax, __shfl_xor(vmax, 4));
        vmax = fmaxf(vmax, __shfl_xor(vmax, 8));
        float mnew = fmaxf(m_r[r], vmax);
        alpha[r] = exp2f(m_r[r] - mnew);
        float rs = 0.f;
#pragma unroll
        for (int n = 0; n < 4; ++n) {
          float pp = exp2f(sv[n][r] - mnew);
          sv[n][r] = pp;
          rs += pp;
        }
        rs += __shfl_xor(rs, 1);
        rs += __shfl_xor(rs, 2);
        rs += __shfl_xor(rs, 4);
        rs += __shfl_xor(rs, 8);
        l_r[r] = l_r[r] * alpha[r] + rs;
        m_r[r] = mnew;
      }

#pragma unroll
      for (int n = 0; n < 4; ++n)
#pragma unroll
        for (int r = 0; r < 4; ++r)
          sP[w][(q * 4 + r) * 72 + n * 16 + cl] = f2bf(sv[n][r]);

#pragma unroll
      for (int dn = 0; dn < 4; ++dn) {
        accO[dn][0] *= alpha[0];
        accO[dn][1] *= alpha[1];
        accO[dn][2] *= alpha[2];
        accO[dn][3] *= alpha[3];
      }

      short8 pf[2];
      pf[0] = *(const short8*)(&sP[w][cl * 72 + q * 8]);
      pf[1] = *(const short8*)(&sP[w][cl * 72 + 32 + q * 8]);
#pragma unroll
      for (int dn = 0; dn < 4; ++dn) {
#pragma unroll
        for (int s = 0; s < 2; ++s) {
          short8 vf = *(const short8*)(sVt + (dn * 16 + cl) * 72 + s * 32 + q * 8);
          accO[dn] = __builtin_amdgcn_mfma_f32_16x16x32_bf16(pf[s], vf, accO[dn], 0, 0, 0);
        }
      }
    }

    float invl[4];
#pragma unroll
    for (int r = 0; r < 4; ++r) invl[r] = 1.0f / l_r[r];
#pragma unroll
    for (int dn = 0; dn < 4; ++dn)
#pragma unroll
      for (int r = 0; r < 4; ++r) {
        int row = b * SEQ + qt * 64 + w * 16 + q * 4 + r;
        O[(size_t)row * DIM + h * 64 + dn * 16 + cl] = f2bf(accO[dn][r] * invl[r]);
      }
    __syncthreads();
  }
}

extern "C" void kernel_launch(void* const* d_in, const int* in_sizes, int n_in,
                              void* d_out, int out_size, void* d_ws, size_t ws_size,
                              hipStream_t stream)
{
  const float* x   = (const float*)d_in[0];
  const float* vec = (const float*)d_in[1];
  const float* wq  = (const float*)d_in[2];
  const float* wk  = (const float*)d_in[3];
  const float* wv  = (const float*)d_in[4];
  const float* wo  = (const float*)d_in[5];
  const float* w1  = (const float*)d_in[6];
  const float* w2  = (const float*)d_in[7];
  const float* w3  = (const float*)d_in[8];
  const float* maw = (const float*)d_in[9];
  const float* mab = (const float*)d_in[10];
  const float* mfw = (const float*)d_in[11];
  const float* mfb = (const float*)d_in[12];
  const float* n1w = (const float*)d_in[13];
  const float* n2w = (const float*)d_in[14];
  const float* fc  = (const float*)d_in[15];
  const float* fs  = (const float*)d_in[16];

  char* p = (char*)d_ws;
  auto takeU = [&](size_t elems) { unsigned short* r = (unsigned short*)p; p += elems * 2; return r; };
  auto takeF = [&](size_t elems) { float* r = (float*)p; p += elems * 4; return r; };

  unsigned short* WQKV = takeU((size_t)1536 * 1024);
  unsigned short* WOb  = takeU((size_t)1024 * 1024);
  unsigned short* W13  = takeU((size_t)2048 * 1024);   // row-interleaved w1/w3
  unsigned short* W2b  = takeU((size_t)1024 * 1024);
  unsigned short* WM   = takeU((size_t)6144 * 1024);   // [mod_attn_w | mod_ffn_w]
  unsigned short* SVEC = takeU((size_t)512 * 1024);
  float* MOD  = takeF((size_t)512 * 6144);             // [sh_a|sc_a|gt_a|sh_f|sc_f|gt_f]
  float* H    = takeF((size_t)4096 * 1024);
  unsigned short* XNb  = takeU((size_t)4096 * 1024);
  unsigned short* QKVb = takeU((size_t)4096 * 1536);
  unsigned short* AOb  = takeU((size_t)4096 * 1024);
  unsigned short* HNb  = takeU((size_t)4096 * 1024);
  unsigned short* Gb  = AOb;   // alias: AO dead after WO gemm

  dim3 blk(256);

  CastArgs ca;
  ca.src[0] = wq;  ca.dst[0] = WQKV;                    ca.n[0] = 1024 * 1024; ca.ilv[0] = 0;
  ca.src[1] = wk;  ca.dst[1] = WQKV + 1024 * 1024;      ca.n[1] = 256 * 1024;  ca.ilv[1] = 0;
  ca.src[2] = wv;  ca.dst[2] = WQKV + 1280 * 1024;      ca.n[2] = 256 * 1024;  ca.ilv[2] = 0;
  ca.src[3] = wo;  ca.dst[3] = WOb;                     ca.n[3] = 1024 * 1024; ca.ilv[3] = 0;
  ca.src[4] = w1;  ca.dst[4] = W13;                     ca.n[4] = 1024 * 1024; ca.ilv[4] = 1;
  ca.src[5] = w3;  ca.dst[5] = W13;                     ca.n[5] = 1024 * 1024; ca.ilv[5] = 2;
  ca.src[6] = w2;  ca.dst[6] = W2b;                     ca.n[6] = 1024 * 1024; ca.ilv[6] = 0;
  ca.src[7] = maw; ca.dst[7] = WM;                      ca.n[7] = 3072 * 1024; ca.ilv[7] = 0;
  ca.src[8] = mfw; ca.dst[8] = WM + (size_t)3072 * 1024; ca.n[8] = 3072 * 1024; ca.ilv[8] = 0;
  cast_weights<<<dim3(3072, 9), blk, 0, stream>>>(ca);

  silu_cast<<<512, blk, 0, stream>>>(vec, SVEC, 512 * 1024);

  // merged modulation GEMM -> f32 [512, 6144]  (grid 384)
  mfma_gemm<1><<<dim3(96, 4), blk, 0, stream>>>(SVEC, WM, 512, 6144, 1024,
      MOD, nullptr, mab, mfb, nullptr, nullptr);

  rms_mod<<<4096, blk, 0, stream>>>(x, n1w, MOD, 0, XNb);

  // fused QKV GEMM + RoPE -> packed bf16 [4096,1536]  (grid 768)
  mfma_gemm<0><<<dim3(24, 32), blk, 0, stream>>>(XNb, WQKV, 4096, 1536, 1024,
      nullptr, QKVb, nullptr, nullptr, fc, fs);

  attn_mfma<<<512, blk, 0, stream>>>(QKVb, AOb);

  // h = x + gate_a * (AO @ wo^T) -> f32  (grid 512)
  mfma_gemm<2><<<dim3(16, 32), blk, 0, stream>>>(AOb, WOb, 4096, 1024, 1024,
      H, nullptr, x, MOD + 2048, nullptr, nullptr);

  rms_mod<<<4096, blk, 0, stream>>>(H, n2w, MOD, 3072, HNb);

  // g = silu(hn@w1^T)*(hn@w3^T) fused in epilogue -> bf16 [4096,1024]  (grid 1024)
  mfma_gemm<3><<<dim3(32, 32), blk, 0, stream>>>(HNb, W13, 4096, 2048, 1024,
      nullptr, Gb, nullptr, nullptr, nullptr, nullptr);

  // out = h + gate_f * (g @ w2^T) -> f32  (grid 512)
  mfma_gemm<4><<<dim3(16, 32), blk, 0, stream>>>(Gb, W2b, 4096, 1024, 1024,
      (float*)d_out, nullptr, H, MOD + 5120, nullptr, nullptr);
}